// Round 5
// baseline (990.788 us; speedup 1.0000x reference)
//
#include <hip/hip_runtime.h>
#include <math.h>

#define NQ   12
#define NL   4
#define NT   128
#define AMPS 32   // per-thread amplitudes; amp = (tid<<5) | j
// state bit 11 = tid bit 6 (wave), bits 10..5 = tid bits 5..0 (lane), bits 4..0 = j

using cplx = float2;

__device__ __forceinline__ cplx cmul(cplx a, cplx b) {
    return make_float2(fmaf(a.x, b.x, -a.y * b.y), fmaf(a.x, b.y, a.y * b.x));
}
__device__ __forceinline__ cplx cmadd(cplx a, cplx b, cplx acc) {
    acc.x = fmaf(a.x, b.x, fmaf(-a.y, b.y, acc.x));
    acc.y = fmaf(a.x, b.y, fmaf(a.y, b.x, acc.y));
    return acc;
}
// C = A * B (2x2 complex, row-major m00 m01 m10 m11)
__device__ __forceinline__ void mm2(const cplx* A, const cplx* B, cplx* C) {
    C[0] = cmadd(A[1], B[2], cmul(A[0], B[0]));
    C[1] = cmadd(A[1], B[3], cmul(A[0], B[1]));
    C[2] = cmadd(A[3], B[2], cmul(A[2], B[0]));
    C[3] = cmadd(A[3], B[3], cmul(A[2], B[1]));
}
// PennyLane Rot(phi, theta, omega) = RZ(omega) RY(theta) RZ(phi)
__device__ __forceinline__ void rotmat(float phi, float th, float om, cplx* M) {
    float ct, st_, ca, sa, cd, sd;
    sincosf(0.5f * th, &st_, &ct);
    sincosf(0.5f * (phi + om), &sa, &ca);
    sincosf(0.5f * (phi - om), &sd, &cd);
    M[0] = make_float2(ct * ca, -ct * sa);
    M[1] = make_float2(-st_ * cd, -st_ * sd);
    M[2] = make_float2(st_ * cd, -st_ * sd);
    M[3] = make_float2(ct * ca, ct * sa);
}
__device__ __forceinline__ void rowsel(const cplx* M, bool hi, cplx& Mx, cplx& My) {
    Mx = hi ? M[3] : M[0];
    My = hi ? M[2] : M[1];
}

// gate on a LANE target bit (xor mask XM); per-thread (Mx,My) pre-selected.
template<int XM>
__device__ __forceinline__ void lane_gate(cplx* s, cplx Mx, cplx My) {
    #pragma unroll
    for (int j0 = 0; j0 < AMPS; j0 += 4) {
        cplx pv[4];
        #pragma unroll
        for (int j = 0; j < 4; ++j) {
            pv[j].x = __shfl_xor(s[j0 + j].x, XM, 64);
            pv[j].y = __shfl_xor(s[j0 + j].y, XM, 64);
        }
        #pragma unroll
        for (int j = 0; j < 4; ++j)
            s[j0 + j] = cmadd(My, pv[j], cmul(Mx, s[j0 + j]));
    }
}
// full 2x2 gate on LOCAL bit K, uniform matrix (per-thread)
template<int K>
__device__ __forceinline__ void local_gate(cplx* s, cplx M0, cplx M1, cplx M2, cplx M3) {
    #pragma unroll
    for (int j = 0; j < AMPS; ++j) {
        if ((j >> K) & 1) continue;
        const int i1 = j | (1 << K);
        cplx v0 = s[j], v1 = s[i1];
        s[j]  = cmadd(M1, v1, cmul(M0, v0));
        s[i1] = cmadd(M3, v1, cmul(M2, v0));
    }
}
// controlled pair-gate: control LOCAL bit CB selects A (c=0) or B (c=1), target LOCAL bit TB
template<int CB, int TB>
__device__ __forceinline__ void cgate_local(cplx* s, const cplx* A, const cplx* B) {
    cplx A0 = A[0], A1 = A[1], A2 = A[2], A3 = A[3];
    cplx B0 = B[0], B1 = B[1], B2 = B[2], B3 = B[3];
    #pragma unroll
    for (int j = 0; j < AMPS; ++j) {
        if ((j >> TB) & 1) continue;
        const int i1 = j | (1 << TB);
        cplx v0 = s[j], v1 = s[i1];
        if ((j >> CB) & 1) {
            s[j]  = cmadd(B1, v1, cmul(B0, v0));
            s[i1] = cmadd(B3, v1, cmul(B2, v0));
        } else {
            s[j]  = cmadd(A1, v1, cmul(A0, v0));
            s[i1] = cmadd(A3, v1, cmul(A2, v0));
        }
    }
}

__global__ __launch_bounds__(NT, 5) void qsim_kernel(
    const float* __restrict__ x,      // (B, 4, NQ)
    const float* __restrict__ prot,   // (NL, NQ, 3)
    const float* __restrict__ penta,  // (NL, NQ, 3)
    float* __restrict__ out)          // (B, NQ)
{
    // xbuf doubles as setup scratch (ENC/RM/EM/UU) and as the exchange buffer.
    __shared__ cplx xbuf[1024];       // 8 KB
    __shared__ cplx GA[NL * NQ][4];   // c=0 branch (persistent)
    __shared__ cplx GB[NL * NQ][4];   // c=1 branch (persistent)
    __shared__ cplx ltab[AMPS];       // layer-0 product over wires 7..11
    __shared__ float zred[2][NQ];

    cplx* ENCp = xbuf;                // 48
    cplx* RMp  = xbuf + 48;           // 192
    cplx* EMp  = xbuf + 240;          // 192
    cplx* UUp  = xbuf + 432;          // 192 (ends at 624 < 1024)

    const int tid  = threadIdx.x;
    const int lane = tid & 63;
    const int w    = tid >> 6;        // wave bit = state bit 11 = wire 0
    const int b    = blockIdx.x;

    // ---- per-sample fused encoding: ENC = RY(x3) RZ(x2) RX(x1) RY(x0)
    if (tid < NQ) {
        const int q = tid;
        const float* xb = x + (size_t)b * 4 * NQ;
        const float t0 = xb[q], t1 = xb[NQ + q], t2 = xb[2 * NQ + q], t3 = xb[3 * NQ + q];
        float c, s;
        sincosf(0.5f * t0, &s, &c);
        cplx R0[4] = {{c, 0.f}, {-s, 0.f}, {s, 0.f}, {c, 0.f}};   // RY
        sincosf(0.5f * t1, &s, &c);
        cplx R1[4] = {{c, 0.f}, {0.f, -s}, {0.f, -s}, {c, 0.f}};  // RX
        sincosf(0.5f * t2, &s, &c);
        cplx R2[4] = {{c, -s}, {0.f, 0.f}, {0.f, 0.f}, {c, s}};   // RZ
        sincosf(0.5f * t3, &s, &c);
        cplx R3[4] = {{c, 0.f}, {-s, 0.f}, {s, 0.f}, {c, 0.f}};   // RY
        cplx T1[4], T2[4], E[4];
        mm2(R1, R0, T1);
        mm2(R2, T1, T2);
        mm2(R3, T2, E);
        #pragma unroll
        for (int i = 0; i < 4; ++i) ENCp[q * 4 + i] = E[i];
    }
    if (tid < NL * NQ) {
        cplx M[4];
        rotmat(prot[3 * tid], prot[3 * tid + 1], prot[3 * tid + 2], M);
        #pragma unroll
        for (int i = 0; i < 4; ++i) RMp[tid * 4 + i] = M[i];
        rotmat(penta[3 * tid], penta[3 * tid + 1], penta[3 * tid + 2], M);
        #pragma unroll
        for (int i = 0; i < 4; ++i) EMp[tid * 4 + i] = M[i];
    }
    __syncthreads();
    if (tid < NL * NQ) {
        cplx U[4];
        mm2(RMp + tid * 4, ENCp + (tid % NQ) * 4, U);
        #pragma unroll
        for (int i = 0; i < 4; ++i) UUp[tid * 4 + i] = U[i];
    }
    __syncthreads();
    // ---- fused controlled-gate pairs (validated round 3/4):
    // q<11:  A = U_{q+1}(l) (I for l=0), B = EM * A
    // q==11: A = U_0(l+1)   (I for l=3), B = A * EM
    if (tid < NL * NQ) {
        const int l = tid / NQ, q = tid - l * NQ;
        cplx A[4], B[4];
        if (q < 11) {
            if (l == 0) { A[0] = {1.f,0.f}; A[1] = {0.f,0.f}; A[2] = {0.f,0.f}; A[3] = {1.f,0.f}; }
            else {
                #pragma unroll
                for (int i = 0; i < 4; ++i) A[i] = UUp[(l * NQ + q + 1) * 4 + i];
            }
            mm2(EMp + tid * 4, A, B);
        } else {
            if (l == NL - 1) { A[0] = {1.f,0.f}; A[1] = {0.f,0.f}; A[2] = {0.f,0.f}; A[3] = {1.f,0.f}; }
            else {
                #pragma unroll
                for (int i = 0; i < 4; ++i) A[i] = UUp[((l + 1) * NQ) * 4 + i];
            }
            mm2(A, EMp + tid * 4, B);
        }
        #pragma unroll
        for (int i = 0; i < 4; ++i) { GA[tid][i] = A[i]; GB[tid][i] = B[i]; }
    }
    // ---- layer-0 local-wire product table (wires 7..11 -> j bits 4..0)
    if (tid >= 64 && tid < 64 + AMPS) {
        const int j = tid - 64;
        cplx m = {1.f, 0.f};
        #pragma unroll
        for (int wq = 7; wq < 12; ++wq) {
            const int bit = (j >> (11 - wq)) & 1;
            m = cmul(m, bit ? UUp[wq * 4 + 2] : UUp[wq * 4 + 0]);
        }
        ltab[j] = m;
    }
    // ---- per-thread lane prefix from layer-0 1q gates (reads UU; before xbuf reuse)
    cplx lp = {1.f, 0.f};
    #pragma unroll
    for (int wq = 0; wq < 7; ++wq) {
        const int bit = (tid >> (6 - wq)) & 1;
        lp = cmul(lp, bit ? UUp[wq * 4 + 2] : UUp[wq * 4 + 0]);
    }
    __syncthreads();

    // ---- init: product state
    cplx s[AMPS];
    #pragma unroll
    for (int j = 0; j < AMPS; ++j) s[j] = cmul(lp, ltab[j]);

    // ---- 48 fused controlled-pair gates
    for (int l = 0; l < NL; ++l) {
        const int g = l * NQ;
        // q=0: c wire0 (wave bit), t wire1 = lane bit5 (xor 32)
        {
            const cplx* M = w ? &GB[g + 0][0] : &GA[g + 0][0];
            cplx Mx, My; rowsel(M, (tid >> 5) & 1, Mx, My);
            lane_gate<32>(s, Mx, My);
        }
        // q=1: c lane5, t lane4 (xor 16)
        {
            const cplx* M = ((tid >> 5) & 1) ? &GB[g + 1][0] : &GA[g + 1][0];
            cplx Mx, My; rowsel(M, (tid >> 4) & 1, Mx, My);
            lane_gate<16>(s, Mx, My);
        }
        // q=2: c lane4, t lane3 (xor 8)
        {
            const cplx* M = ((tid >> 4) & 1) ? &GB[g + 2][0] : &GA[g + 2][0];
            cplx Mx, My; rowsel(M, (tid >> 3) & 1, Mx, My);
            lane_gate<8>(s, Mx, My);
        }
        // q=3: c lane3, t lane2 (xor 4)
        {
            const cplx* M = ((tid >> 3) & 1) ? &GB[g + 3][0] : &GA[g + 3][0];
            cplx Mx, My; rowsel(M, (tid >> 2) & 1, Mx, My);
            lane_gate<4>(s, Mx, My);
        }
        // q=4: c lane2, t lane1 (xor 2)
        {
            const cplx* M = ((tid >> 2) & 1) ? &GB[g + 4][0] : &GA[g + 4][0];
            cplx Mx, My; rowsel(M, (tid >> 1) & 1, Mx, My);
            lane_gate<2>(s, Mx, My);
        }
        // q=5: c lane1, t lane0 (xor 1)
        {
            const cplx* M = ((tid >> 1) & 1) ? &GB[g + 5][0] : &GA[g + 5][0];
            cplx Mx, My; rowsel(M, tid & 1, Mx, My);
            lane_gate<1>(s, Mx, My);
        }
        // q=6: c lane0, t local bit4
        {
            const cplx* M = (tid & 1) ? &GB[g + 6][0] : &GA[g + 6][0];
            local_gate<4>(s, M[0], M[1], M[2], M[3]);
        }
        // q=7..10: both local
        cgate_local<4, 3>(s, &GA[g + 7][0], &GB[g + 7][0]);
        cgate_local<3, 2>(s, &GA[g + 8][0], &GB[g + 8][0]);
        cgate_local<2, 1>(s, &GA[g + 9][0], &GB[g + 9][0]);
        cgate_local<1, 0>(s, &GA[g + 10][0], &GB[g + 10][0]);
        // q=11: c local bit0 (j parity), t wire0 = wave bit -> LDS exchange with tid^64
        // 4 rounds x 8 amps, packed as float4 pairs (even amp -> A, odd -> B)
        {
            cplx Ax, Ay, Bx, By;
            rowsel(&GA[g + 11][0], w, Ax, Ay);
            rowsel(&GB[g + 11][0], w, Bx, By);
            float4* xb4 = (float4*)xbuf;
            #pragma unroll
            for (int r = 0; r < 4; ++r) {
                __syncthreads();
                #pragma unroll
                for (int j2 = 0; j2 < 4; ++j2) {
                    const int j = r * 8 + 2 * j2;
                    xb4[j2 * NT + tid] = make_float4(s[j].x, s[j].y, s[j + 1].x, s[j + 1].y);
                }
                __syncthreads();
                #pragma unroll
                for (int j2 = 0; j2 < 4; ++j2) {
                    float4 f = xb4[j2 * NT + (tid ^ 64)];
                    const int j = r * 8 + 2 * j2;
                    s[j]     = cmadd(Ay, make_float2(f.x, f.y), cmul(Ax, s[j]));
                    s[j + 1] = cmadd(By, make_float2(f.z, f.w), cmul(Bx, s[j + 1]));
                }
            }
        }
    }

    // ---- measurement
    float psum = 0.f;
    float zl0 = 0.f, zl1 = 0.f, zl2 = 0.f, zl3 = 0.f, zl4 = 0.f;  // wires 7..11
    #pragma unroll
    for (int j = 0; j < AMPS; ++j) {
        cplx v = s[j];
        float pr = fmaf(v.x, v.x, v.y * v.y);
        psum += pr;
        int pb = __float_as_int(pr);
        zl0 += __int_as_float(pb ^ (((j >> 4) & 1) << 31));
        zl1 += __int_as_float(pb ^ (((j >> 3) & 1) << 31));
        zl2 += __int_as_float(pb ^ (((j >> 2) & 1) << 31));
        zl3 += __int_as_float(pb ^ (((j >> 1) & 1) << 31));
        zl4 += __int_as_float(pb ^ ((j & 1) << 31));
    }
    float zv[NQ];
    #pragma unroll
    for (int i = 0; i < 7; ++i)                       // wires 0..6: sign = tid bit (6-i)
        zv[i] = ((tid >> (6 - i)) & 1) ? -psum : psum;
    zv[7] = zl0; zv[8] = zl1; zv[9] = zl2; zv[10] = zl3; zv[11] = zl4;
    #pragma unroll
    for (int q = 0; q < NQ; ++q) {
        float v = zv[q];
        #pragma unroll
        for (int off = 32; off > 0; off >>= 1) v += __shfl_xor(v, off, 64);
        zv[q] = v;
    }
    if (lane == 0) {
        #pragma unroll
        for (int q = 0; q < NQ; ++q) zred[w][q] = zv[q];
    }
    __syncthreads();
    if (tid < NQ)
        out[(size_t)b * NQ + tid] = zred[0][tid] + zred[1][tid];
}

extern "C" void kernel_launch(void* const* d_in, const int* in_sizes, int n_in,
                              void* d_out, int out_size, void* d_ws, size_t ws_size,
                              hipStream_t stream) {
    const float* x     = (const float*)d_in[0];
    const float* prot  = (const float*)d_in[1];
    const float* penta = (const float*)d_in[2];
    float* out = (float*)d_out;
    const int B = in_sizes[0] / (4 * NQ);   // 4096
    qsim_kernel<<<B, NT, 0, stream>>>(x, prot, penta, out);
}

// Round 6
// 240.869 us; speedup vs baseline: 4.1134x; 4.1134x over previous
//
#include <hip/hip_runtime.h>
#include <math.h>

#define NQ   12
#define NL   4
#define NT   128
#define AMPS 32   // per-thread amplitudes; amp = (tid<<5) | j
// state bit 11 = tid bit 6 (wave), bits 10..5 = tid bits 5..0 (lane), bits 4..0 = j

using cplx = float2;

__device__ __forceinline__ cplx cmul(cplx a, cplx b) {
    return make_float2(fmaf(a.x, b.x, -a.y * b.y), fmaf(a.x, b.y, a.y * b.x));
}
__device__ __forceinline__ cplx cmadd(cplx a, cplx b, cplx acc) {
    acc.x = fmaf(a.x, b.x, fmaf(-a.y, b.y, acc.x));
    acc.y = fmaf(a.x, b.y, fmaf(a.y, b.x, acc.y));
    return acc;
}
// C = A * B (2x2 complex, row-major m00 m01 m10 m11)
__device__ __forceinline__ void mm2(const cplx* A, const cplx* B, cplx* C) {
    C[0] = cmadd(A[1], B[2], cmul(A[0], B[0]));
    C[1] = cmadd(A[1], B[3], cmul(A[0], B[1]));
    C[2] = cmadd(A[3], B[2], cmul(A[2], B[0]));
    C[3] = cmadd(A[3], B[3], cmul(A[2], B[1]));
}
// PennyLane Rot(phi, theta, omega) = RZ(omega) RY(theta) RZ(phi)
__device__ __forceinline__ void rotmat(float phi, float th, float om, cplx* M) {
    float ct, st_, ca, sa, cd, sd;
    sincosf(0.5f * th, &st_, &ct);
    sincosf(0.5f * (phi + om), &sa, &ca);
    sincosf(0.5f * (phi - om), &sd, &cd);
    M[0] = make_float2(ct * ca, -ct * sa);
    M[1] = make_float2(-st_ * cd, -st_ * sd);
    M[2] = make_float2(st_ * cd, -st_ * sd);
    M[3] = make_float2(ct * ca, ct * sa);
}
__device__ __forceinline__ void rowsel(const cplx* M, bool hi, cplx& Mx, cplx& My) {
    Mx = hi ? M[3] : M[0];
    My = hi ? M[2] : M[1];
}

// gate on a LANE target bit (xor mask XM); per-thread (Mx,My) pre-selected.
template<int XM>
__device__ __forceinline__ void lane_gate(cplx* s, cplx Mx, cplx My) {
    #pragma unroll
    for (int j0 = 0; j0 < AMPS; j0 += 4) {
        cplx pv[4];
        #pragma unroll
        for (int j = 0; j < 4; ++j) {
            pv[j].x = __shfl_xor(s[j0 + j].x, XM, 64);
            pv[j].y = __shfl_xor(s[j0 + j].y, XM, 64);
        }
        #pragma unroll
        for (int j = 0; j < 4; ++j)
            s[j0 + j] = cmadd(My, pv[j], cmul(Mx, s[j0 + j]));
    }
}
// full 2x2 gate on LOCAL bit K, uniform matrix (per-thread)
template<int K>
__device__ __forceinline__ void local_gate(cplx* s, cplx M0, cplx M1, cplx M2, cplx M3) {
    #pragma unroll
    for (int j = 0; j < AMPS; ++j) {
        if ((j >> K) & 1) continue;
        const int i1 = j | (1 << K);
        cplx v0 = s[j], v1 = s[i1];
        s[j]  = cmadd(M1, v1, cmul(M0, v0));
        s[i1] = cmadd(M3, v1, cmul(M2, v0));
    }
}
// controlled pair-gate: control LOCAL bit CB selects A (c=0) or B (c=1), target LOCAL bit TB
template<int CB, int TB>
__device__ __forceinline__ void cgate_local(cplx* s, const cplx* A, const cplx* B) {
    cplx A0 = A[0], A1 = A[1], A2 = A[2], A3 = A[3];
    cplx B0 = B[0], B1 = B[1], B2 = B[2], B3 = B[3];
    #pragma unroll
    for (int j = 0; j < AMPS; ++j) {
        if ((j >> TB) & 1) continue;
        const int i1 = j | (1 << TB);
        cplx v0 = s[j], v1 = s[i1];
        if ((j >> CB) & 1) {
            s[j]  = cmadd(B1, v1, cmul(B0, v0));
            s[i1] = cmadd(B3, v1, cmul(B2, v0));
        } else {
            s[j]  = cmadd(A1, v1, cmul(A0, v0));
            s[i1] = cmadd(A3, v1, cmul(A2, v0));
        }
    }
}

__global__ __launch_bounds__(NT, 4) void qsim_kernel(
    const float* __restrict__ x,      // (B, 4, NQ)
    const float* __restrict__ prot,   // (NL, NQ, 3)
    const float* __restrict__ penta,  // (NL, NQ, 3)
    float* __restrict__ out)          // (B, NQ)
{
    // xbuf doubles as setup scratch (ENC/RM/EM/UU) and as the exchange buffer.
    __shared__ cplx xbuf[1024];       // 8 KB
    __shared__ cplx GA[NL * NQ][4];   // c=0 branch (persistent)
    __shared__ cplx GB[NL * NQ][4];   // c=1 branch (persistent)
    __shared__ cplx ltab[AMPS];       // layer-0 product over wires 7..11
    __shared__ float zred[2][NQ];

    cplx* ENCp = xbuf;                // 48
    cplx* RMp  = xbuf + 48;           // 192
    cplx* EMp  = xbuf + 240;          // 192
    cplx* UUp  = xbuf + 432;          // 192 (ends at 624 < 1024)

    const int tid  = threadIdx.x;
    const int lane = tid & 63;
    const int w    = tid >> 6;        // wave bit = state bit 11 = wire 0
    const int b    = blockIdx.x;

    // ---- per-sample fused encoding: ENC = RY(x3) RZ(x2) RX(x1) RY(x0)
    if (tid < NQ) {
        const int q = tid;
        const float* xb = x + (size_t)b * 4 * NQ;
        const float t0 = xb[q], t1 = xb[NQ + q], t2 = xb[2 * NQ + q], t3 = xb[3 * NQ + q];
        float c, s;
        sincosf(0.5f * t0, &s, &c);
        cplx R0[4] = {{c, 0.f}, {-s, 0.f}, {s, 0.f}, {c, 0.f}};   // RY
        sincosf(0.5f * t1, &s, &c);
        cplx R1[4] = {{c, 0.f}, {0.f, -s}, {0.f, -s}, {c, 0.f}};  // RX
        sincosf(0.5f * t2, &s, &c);
        cplx R2[4] = {{c, -s}, {0.f, 0.f}, {0.f, 0.f}, {c, s}};   // RZ
        sincosf(0.5f * t3, &s, &c);
        cplx R3[4] = {{c, 0.f}, {-s, 0.f}, {s, 0.f}, {c, 0.f}};   // RY
        cplx T1[4], T2[4], E[4];
        mm2(R1, R0, T1);
        mm2(R2, T1, T2);
        mm2(R3, T2, E);
        #pragma unroll
        for (int i = 0; i < 4; ++i) ENCp[q * 4 + i] = E[i];
    }
    if (tid < NL * NQ) {
        cplx M[4];
        rotmat(prot[3 * tid], prot[3 * tid + 1], prot[3 * tid + 2], M);
        #pragma unroll
        for (int i = 0; i < 4; ++i) RMp[tid * 4 + i] = M[i];
        rotmat(penta[3 * tid], penta[3 * tid + 1], penta[3 * tid + 2], M);
        #pragma unroll
        for (int i = 0; i < 4; ++i) EMp[tid * 4 + i] = M[i];
    }
    __syncthreads();
    if (tid < NL * NQ) {
        cplx U[4];
        mm2(RMp + tid * 4, ENCp + (tid % NQ) * 4, U);
        #pragma unroll
        for (int i = 0; i < 4; ++i) UUp[tid * 4 + i] = U[i];
    }
    __syncthreads();
    // ---- fused controlled-gate pairs (validated round 3/4):
    // q<11:  A = U_{q+1}(l) (I for l=0), B = EM * A
    // q==11: A = U_0(l+1)   (I for l=3), B = A * EM
    if (tid < NL * NQ) {
        const int l = tid / NQ, q = tid - l * NQ;
        cplx A[4], B[4];
        if (q < 11) {
            if (l == 0) { A[0] = {1.f,0.f}; A[1] = {0.f,0.f}; A[2] = {0.f,0.f}; A[3] = {1.f,0.f}; }
            else {
                #pragma unroll
                for (int i = 0; i < 4; ++i) A[i] = UUp[(l * NQ + q + 1) * 4 + i];
            }
            mm2(EMp + tid * 4, A, B);
        } else {
            if (l == NL - 1) { A[0] = {1.f,0.f}; A[1] = {0.f,0.f}; A[2] = {0.f,0.f}; A[3] = {1.f,0.f}; }
            else {
                #pragma unroll
                for (int i = 0; i < 4; ++i) A[i] = UUp[((l + 1) * NQ) * 4 + i];
            }
            mm2(A, EMp + tid * 4, B);
        }
        #pragma unroll
        for (int i = 0; i < 4; ++i) { GA[tid][i] = A[i]; GB[tid][i] = B[i]; }
    }
    // ---- layer-0 local-wire product table (wires 7..11 -> j bits 4..0)
    if (tid >= 64 && tid < 64 + AMPS) {
        const int j = tid - 64;
        cplx m = {1.f, 0.f};
        #pragma unroll
        for (int wq = 7; wq < 12; ++wq) {
            const int bit = (j >> (11 - wq)) & 1;
            m = cmul(m, bit ? UUp[wq * 4 + 2] : UUp[wq * 4 + 0]);
        }
        ltab[j] = m;
    }
    // ---- per-thread lane prefix from layer-0 1q gates (reads UU; before xbuf reuse)
    cplx lp = {1.f, 0.f};
    #pragma unroll
    for (int wq = 0; wq < 7; ++wq) {
        const int bit = (tid >> (6 - wq)) & 1;
        lp = cmul(lp, bit ? UUp[wq * 4 + 2] : UUp[wq * 4 + 0]);
    }
    __syncthreads();

    // ---- init: product state
    cplx s[AMPS];
    #pragma unroll
    for (int j = 0; j < AMPS; ++j) s[j] = cmul(lp, ltab[j]);

    // ---- 48 fused controlled-pair gates
    for (int l = 0; l < NL; ++l) {
        const int g = l * NQ;
        // q=0: c wire0 (wave bit), t wire1 = lane bit5 (xor 32)
        {
            const cplx* M = w ? &GB[g + 0][0] : &GA[g + 0][0];
            cplx Mx, My; rowsel(M, (tid >> 5) & 1, Mx, My);
            lane_gate<32>(s, Mx, My);
        }
        // q=1: c lane5, t lane4 (xor 16)
        {
            const cplx* M = ((tid >> 5) & 1) ? &GB[g + 1][0] : &GA[g + 1][0];
            cplx Mx, My; rowsel(M, (tid >> 4) & 1, Mx, My);
            lane_gate<16>(s, Mx, My);
        }
        // q=2: c lane4, t lane3 (xor 8)
        {
            const cplx* M = ((tid >> 4) & 1) ? &GB[g + 2][0] : &GA[g + 2][0];
            cplx Mx, My; rowsel(M, (tid >> 3) & 1, Mx, My);
            lane_gate<8>(s, Mx, My);
        }
        // q=3: c lane3, t lane2 (xor 4)
        {
            const cplx* M = ((tid >> 3) & 1) ? &GB[g + 3][0] : &GA[g + 3][0];
            cplx Mx, My; rowsel(M, (tid >> 2) & 1, Mx, My);
            lane_gate<4>(s, Mx, My);
        }
        // q=4: c lane2, t lane1 (xor 2)
        {
            const cplx* M = ((tid >> 2) & 1) ? &GB[g + 4][0] : &GA[g + 4][0];
            cplx Mx, My; rowsel(M, (tid >> 1) & 1, Mx, My);
            lane_gate<2>(s, Mx, My);
        }
        // q=5: c lane1, t lane0 (xor 1)
        {
            const cplx* M = ((tid >> 1) & 1) ? &GB[g + 5][0] : &GA[g + 5][0];
            cplx Mx, My; rowsel(M, tid & 1, Mx, My);
            lane_gate<1>(s, Mx, My);
        }
        // q=6: c lane0, t local bit4
        {
            const cplx* M = (tid & 1) ? &GB[g + 6][0] : &GA[g + 6][0];
            local_gate<4>(s, M[0], M[1], M[2], M[3]);
        }
        // q=7..10: both local
        cgate_local<4, 3>(s, &GA[g + 7][0], &GB[g + 7][0]);
        cgate_local<3, 2>(s, &GA[g + 8][0], &GB[g + 8][0]);
        cgate_local<2, 1>(s, &GA[g + 9][0], &GB[g + 9][0]);
        cgate_local<1, 0>(s, &GA[g + 10][0], &GB[g + 10][0]);
        // q=11: c local bit0 (j parity), t wire0 = wave bit -> LDS exchange with tid^64
        // 4 rounds x 8 amps, packed as float4 pairs (even amp -> A, odd -> B)
        {
            cplx Ax, Ay, Bx, By;
            rowsel(&GA[g + 11][0], w, Ax, Ay);
            rowsel(&GB[g + 11][0], w, Bx, By);
            float4* xb4 = (float4*)xbuf;
            #pragma unroll
            for (int r = 0; r < 4; ++r) {
                __syncthreads();
                #pragma unroll
                for (int j2 = 0; j2 < 4; ++j2) {
                    const int j = r * 8 + 2 * j2;
                    xb4[j2 * NT + tid] = make_float4(s[j].x, s[j].y, s[j + 1].x, s[j + 1].y);
                }
                __syncthreads();
                #pragma unroll
                for (int j2 = 0; j2 < 4; ++j2) {
                    float4 f = xb4[j2 * NT + (tid ^ 64)];
                    const int j = r * 8 + 2 * j2;
                    s[j]     = cmadd(Ay, make_float2(f.x, f.y), cmul(Ax, s[j]));
                    s[j + 1] = cmadd(By, make_float2(f.z, f.w), cmul(Bx, s[j + 1]));
                }
            }
        }
    }

    // ---- measurement
    float psum = 0.f;
    float zl0 = 0.f, zl1 = 0.f, zl2 = 0.f, zl3 = 0.f, zl4 = 0.f;  // wires 7..11
    #pragma unroll
    for (int j = 0; j < AMPS; ++j) {
        cplx v = s[j];
        float pr = fmaf(v.x, v.x, v.y * v.y);
        psum += pr;
        int pb = __float_as_int(pr);
        zl0 += __int_as_float(pb ^ (((j >> 4) & 1) << 31));
        zl1 += __int_as_float(pb ^ (((j >> 3) & 1) << 31));
        zl2 += __int_as_float(pb ^ (((j >> 2) & 1) << 31));
        zl3 += __int_as_float(pb ^ (((j >> 1) & 1) << 31));
        zl4 += __int_as_float(pb ^ ((j & 1) << 31));
    }
    float zv[NQ];
    #pragma unroll
    for (int i = 0; i < 7; ++i)                       // wires 0..6: sign = tid bit (6-i)
        zv[i] = ((tid >> (6 - i)) & 1) ? -psum : psum;
    zv[7] = zl0; zv[8] = zl1; zv[9] = zl2; zv[10] = zl3; zv[11] = zl4;
    #pragma unroll
    for (int q = 0; q < NQ; ++q) {
        float v = zv[q];
        #pragma unroll
        for (int off = 32; off > 0; off >>= 1) v += __shfl_xor(v, off, 64);
        zv[q] = v;
    }
    if (lane == 0) {
        #pragma unroll
        for (int q = 0; q < NQ; ++q) zred[w][q] = zv[q];
    }
    __syncthreads();
    if (tid < NQ)
        out[(size_t)b * NQ + tid] = zred[0][tid] + zred[1][tid];
}

extern "C" void kernel_launch(void* const* d_in, const int* in_sizes, int n_in,
                              void* d_out, int out_size, void* d_ws, size_t ws_size,
                              hipStream_t stream) {
    const float* x     = (const float*)d_in[0];
    const float* prot  = (const float*)d_in[1];
    const float* penta = (const float*)d_in[2];
    float* out = (float*)d_out;
    const int B = in_sizes[0] / (4 * NQ);   // 4096
    qsim_kernel<<<B, NT, 0, stream>>>(x, prot, penta, out);
}

// Round 7
// 193.902 us; speedup vs baseline: 5.1097x; 1.2422x over previous
//
#include <hip/hip_runtime.h>
#include <math.h>

#define NQ   12
#define NL   4
#define NT   128
#define AMPS 32   // per-thread amplitudes; amp = (tid<<5) | j
// state bit 11 = tid bit 6 (wave), bits 10..5 = tid bits 5..0 (lane), bits 4..0 = j

using cplx = float2;

__device__ __forceinline__ cplx cmul(cplx a, cplx b) {
    return make_float2(fmaf(a.x, b.x, -a.y * b.y), fmaf(a.x, b.y, a.y * b.x));
}
__device__ __forceinline__ cplx cmadd(cplx a, cplx b, cplx acc) {
    acc.x = fmaf(a.x, b.x, fmaf(-a.y, b.y, acc.x));
    acc.y = fmaf(a.x, b.y, fmaf(a.y, b.x, acc.y));
    return acc;
}
// C = A * B (2x2 complex, row-major m00 m01 m10 m11)
__device__ __forceinline__ void mm2(const cplx* A, const cplx* B, cplx* C) {
    C[0] = cmadd(A[1], B[2], cmul(A[0], B[0]));
    C[1] = cmadd(A[1], B[3], cmul(A[0], B[1]));
    C[2] = cmadd(A[3], B[2], cmul(A[2], B[0]));
    C[3] = cmadd(A[3], B[3], cmul(A[2], B[1]));
}
// PennyLane Rot(phi, theta, omega) = RZ(omega) RY(theta) RZ(phi)
__device__ __forceinline__ void rotmat(float phi, float th, float om, cplx* M) {
    float ct, st_, ca, sa, cd, sd;
    sincosf(0.5f * th, &st_, &ct);
    sincosf(0.5f * (phi + om), &sa, &ca);
    sincosf(0.5f * (phi - om), &sd, &cd);
    M[0] = make_float2(ct * ca, -ct * sa);
    M[1] = make_float2(-st_ * cd, -st_ * sd);
    M[2] = make_float2(st_ * cd, -st_ * sd);
    M[3] = make_float2(ct * ca, ct * sa);
}
__device__ __forceinline__ void rowsel(const cplx* M, bool hi, cplx& Mx, cplx& My) {
    Mx = hi ? M[3] : M[0];
    My = hi ? M[2] : M[1];
}

// gate on a LANE target bit (xor mask XM); per-thread (Mx,My) pre-selected.
template<int XM>
__device__ __forceinline__ void lane_gate(cplx* s, cplx Mx, cplx My) {
    #pragma unroll
    for (int j0 = 0; j0 < AMPS; j0 += 4) {
        cplx pv[4];
        #pragma unroll
        for (int j = 0; j < 4; ++j) {
            pv[j].x = __shfl_xor(s[j0 + j].x, XM, 64);
            pv[j].y = __shfl_xor(s[j0 + j].y, XM, 64);
        }
        #pragma unroll
        for (int j = 0; j < 4; ++j)
            s[j0 + j] = cmadd(My, pv[j], cmul(Mx, s[j0 + j]));
    }
}
// full 2x2 gate on LOCAL bit K, uniform matrix (per-thread)
template<int K>
__device__ __forceinline__ void local_gate(cplx* s, cplx M0, cplx M1, cplx M2, cplx M3) {
    #pragma unroll
    for (int j = 0; j < AMPS; ++j) {
        if ((j >> K) & 1) continue;
        const int i1 = j | (1 << K);
        cplx v0 = s[j], v1 = s[i1];
        s[j]  = cmadd(M1, v1, cmul(M0, v0));
        s[i1] = cmadd(M3, v1, cmul(M2, v0));
    }
}
// controlled pair-gate: control LOCAL bit CB selects A (c=0) or B (c=1), target LOCAL bit TB
template<int CB, int TB>
__device__ __forceinline__ void cgate_local(cplx* s, const cplx* A, const cplx* B) {
    cplx A0 = A[0], A1 = A[1], A2 = A[2], A3 = A[3];
    cplx B0 = B[0], B1 = B[1], B2 = B[2], B3 = B[3];
    #pragma unroll
    for (int j = 0; j < AMPS; ++j) {
        if ((j >> TB) & 1) continue;
        const int i1 = j | (1 << TB);
        cplx v0 = s[j], v1 = s[i1];
        if ((j >> CB) & 1) {
            s[j]  = cmadd(B1, v1, cmul(B0, v0));
            s[i1] = cmadd(B3, v1, cmul(B2, v0));
        } else {
            s[j]  = cmadd(A1, v1, cmul(A0, v0));
            s[i1] = cmadd(A3, v1, cmul(A2, v0));
        }
    }
}

__global__ __launch_bounds__(NT, 2) void qsim_kernel(
    const float* __restrict__ x,      // (B, 4, NQ)
    const float* __restrict__ prot,   // (NL, NQ, 3)
    const float* __restrict__ penta,  // (NL, NQ, 3)
    float* __restrict__ out)          // (B, NQ)
{
    // xbuf doubles as setup scratch (ENC/RM/EM/UU) and as the exchange buffer.
    __shared__ cplx xbuf[1024];       // 8 KB
    __shared__ cplx GA[NL * NQ][4];   // c=0 branch (persistent)
    __shared__ cplx GB[NL * NQ][4];   // c=1 branch (persistent)
    __shared__ cplx ltab[AMPS];       // layer-0 product over wires 7..11
    __shared__ float zred[2][NQ];

    cplx* ENCp = xbuf;                // 48
    cplx* RMp  = xbuf + 48;           // 192
    cplx* EMp  = xbuf + 240;          // 192
    cplx* UUp  = xbuf + 432;          // 192 (ends at 624 < 1024)

    const int tid  = threadIdx.x;
    const int lane = tid & 63;
    const int w    = tid >> 6;        // wave bit = state bit 11 = wire 0
    const int b    = blockIdx.x;

    // ---- per-sample fused encoding: ENC = RY(x3) RZ(x2) RX(x1) RY(x0)
    if (tid < NQ) {
        const int q = tid;
        const float* xb = x + (size_t)b * 4 * NQ;
        const float t0 = xb[q], t1 = xb[NQ + q], t2 = xb[2 * NQ + q], t3 = xb[3 * NQ + q];
        float c, s;
        sincosf(0.5f * t0, &s, &c);
        cplx R0[4] = {{c, 0.f}, {-s, 0.f}, {s, 0.f}, {c, 0.f}};   // RY
        sincosf(0.5f * t1, &s, &c);
        cplx R1[4] = {{c, 0.f}, {0.f, -s}, {0.f, -s}, {c, 0.f}};  // RX
        sincosf(0.5f * t2, &s, &c);
        cplx R2[4] = {{c, -s}, {0.f, 0.f}, {0.f, 0.f}, {c, s}};   // RZ
        sincosf(0.5f * t3, &s, &c);
        cplx R3[4] = {{c, 0.f}, {-s, 0.f}, {s, 0.f}, {c, 0.f}};   // RY
        cplx T1[4], T2[4], E[4];
        mm2(R1, R0, T1);
        mm2(R2, T1, T2);
        mm2(R3, T2, E);
        #pragma unroll
        for (int i = 0; i < 4; ++i) ENCp[q * 4 + i] = E[i];
    }
    if (tid < NL * NQ) {
        cplx M[4];
        rotmat(prot[3 * tid], prot[3 * tid + 1], prot[3 * tid + 2], M);
        #pragma unroll
        for (int i = 0; i < 4; ++i) RMp[tid * 4 + i] = M[i];
        rotmat(penta[3 * tid], penta[3 * tid + 1], penta[3 * tid + 2], M);
        #pragma unroll
        for (int i = 0; i < 4; ++i) EMp[tid * 4 + i] = M[i];
    }
    __syncthreads();
    if (tid < NL * NQ) {
        cplx U[4];
        mm2(RMp + tid * 4, ENCp + (tid % NQ) * 4, U);
        #pragma unroll
        for (int i = 0; i < 4; ++i) UUp[tid * 4 + i] = U[i];
    }
    __syncthreads();
    // ---- fused controlled-gate pairs (validated round 3/4):
    // q<11:  A = U_{q+1}(l) (I for l=0), B = EM * A
    // q==11: A = U_0(l+1)   (I for l=3), B = A * EM
    if (tid < NL * NQ) {
        const int l = tid / NQ, q = tid - l * NQ;
        cplx A[4], B[4];
        if (q < 11) {
            if (l == 0) { A[0] = {1.f,0.f}; A[1] = {0.f,0.f}; A[2] = {0.f,0.f}; A[3] = {1.f,0.f}; }
            else {
                #pragma unroll
                for (int i = 0; i < 4; ++i) A[i] = UUp[(l * NQ + q + 1) * 4 + i];
            }
            mm2(EMp + tid * 4, A, B);
        } else {
            if (l == NL - 1) { A[0] = {1.f,0.f}; A[1] = {0.f,0.f}; A[2] = {0.f,0.f}; A[3] = {1.f,0.f}; }
            else {
                #pragma unroll
                for (int i = 0; i < 4; ++i) A[i] = UUp[((l + 1) * NQ) * 4 + i];
            }
            mm2(A, EMp + tid * 4, B);
        }
        #pragma unroll
        for (int i = 0; i < 4; ++i) { GA[tid][i] = A[i]; GB[tid][i] = B[i]; }
    }
    // ---- layer-0 local-wire product table (wires 7..11 -> j bits 4..0)
    if (tid >= 64 && tid < 64 + AMPS) {
        const int j = tid - 64;
        cplx m = {1.f, 0.f};
        #pragma unroll
        for (int wq = 7; wq < 12; ++wq) {
            const int bit = (j >> (11 - wq)) & 1;
            m = cmul(m, bit ? UUp[wq * 4 + 2] : UUp[wq * 4 + 0]);
        }
        ltab[j] = m;
    }
    // ---- per-thread lane prefix from layer-0 1q gates (reads UU; before xbuf reuse)
    cplx lp = {1.f, 0.f};
    #pragma unroll
    for (int wq = 0; wq < 7; ++wq) {
        const int bit = (tid >> (6 - wq)) & 1;
        lp = cmul(lp, bit ? UUp[wq * 4 + 2] : UUp[wq * 4 + 0]);
    }
    __syncthreads();

    // ---- init: product state
    cplx s[AMPS];
    #pragma unroll
    for (int j = 0; j < AMPS; ++j) s[j] = cmul(lp, ltab[j]);

    // ---- 48 fused controlled-pair gates
    for (int l = 0; l < NL; ++l) {
        const int g = l * NQ;
        // q=0: c wire0 (wave bit), t wire1 = lane bit5 (xor 32)
        {
            const cplx* M = w ? &GB[g + 0][0] : &GA[g + 0][0];
            cplx Mx, My; rowsel(M, (tid >> 5) & 1, Mx, My);
            lane_gate<32>(s, Mx, My);
        }
        // q=1: c lane5, t lane4 (xor 16)
        {
            const cplx* M = ((tid >> 5) & 1) ? &GB[g + 1][0] : &GA[g + 1][0];
            cplx Mx, My; rowsel(M, (tid >> 4) & 1, Mx, My);
            lane_gate<16>(s, Mx, My);
        }
        // q=2: c lane4, t lane3 (xor 8)
        {
            const cplx* M = ((tid >> 4) & 1) ? &GB[g + 2][0] : &GA[g + 2][0];
            cplx Mx, My; rowsel(M, (tid >> 3) & 1, Mx, My);
            lane_gate<8>(s, Mx, My);
        }
        // q=3: c lane3, t lane2 (xor 4)
        {
            const cplx* M = ((tid >> 3) & 1) ? &GB[g + 3][0] : &GA[g + 3][0];
            cplx Mx, My; rowsel(M, (tid >> 2) & 1, Mx, My);
            lane_gate<4>(s, Mx, My);
        }
        // q=4: c lane2, t lane1 (xor 2)
        {
            const cplx* M = ((tid >> 2) & 1) ? &GB[g + 4][0] : &GA[g + 4][0];
            cplx Mx, My; rowsel(M, (tid >> 1) & 1, Mx, My);
            lane_gate<2>(s, Mx, My);
        }
        // q=5: c lane1, t lane0 (xor 1)
        {
            const cplx* M = ((tid >> 1) & 1) ? &GB[g + 5][0] : &GA[g + 5][0];
            cplx Mx, My; rowsel(M, tid & 1, Mx, My);
            lane_gate<1>(s, Mx, My);
        }
        // q=6: c lane0, t local bit4
        {
            const cplx* M = (tid & 1) ? &GB[g + 6][0] : &GA[g + 6][0];
            local_gate<4>(s, M[0], M[1], M[2], M[3]);
        }
        // q=7..10: both local
        cgate_local<4, 3>(s, &GA[g + 7][0], &GB[g + 7][0]);
        cgate_local<3, 2>(s, &GA[g + 8][0], &GB[g + 8][0]);
        cgate_local<2, 1>(s, &GA[g + 9][0], &GB[g + 9][0]);
        cgate_local<1, 0>(s, &GA[g + 10][0], &GB[g + 10][0]);
        // q=11: c local bit0 (j parity), t wire0 = wave bit -> LDS exchange with tid^64
        // 4 rounds x 8 amps, packed as float4 pairs (even amp -> A, odd -> B)
        {
            cplx Ax, Ay, Bx, By;
            rowsel(&GA[g + 11][0], w, Ax, Ay);
            rowsel(&GB[g + 11][0], w, Bx, By);
            float4* xb4 = (float4*)xbuf;
            #pragma unroll
            for (int r = 0; r < 4; ++r) {
                __syncthreads();
                #pragma unroll
                for (int j2 = 0; j2 < 4; ++j2) {
                    const int j = r * 8 + 2 * j2;
                    xb4[j2 * NT + tid] = make_float4(s[j].x, s[j].y, s[j + 1].x, s[j + 1].y);
                }
                __syncthreads();
                #pragma unroll
                for (int j2 = 0; j2 < 4; ++j2) {
                    float4 f = xb4[j2 * NT + (tid ^ 64)];
                    const int j = r * 8 + 2 * j2;
                    s[j]     = cmadd(Ay, make_float2(f.x, f.y), cmul(Ax, s[j]));
                    s[j + 1] = cmadd(By, make_float2(f.z, f.w), cmul(Bx, s[j + 1]));
                }
            }
        }
    }

    // ---- measurement
    float psum = 0.f;
    float zl0 = 0.f, zl1 = 0.f, zl2 = 0.f, zl3 = 0.f, zl4 = 0.f;  // wires 7..11
    #pragma unroll
    for (int j = 0; j < AMPS; ++j) {
        cplx v = s[j];
        float pr = fmaf(v.x, v.x, v.y * v.y);
        psum += pr;
        int pb = __float_as_int(pr);
        zl0 += __int_as_float(pb ^ (((j >> 4) & 1) << 31));
        zl1 += __int_as_float(pb ^ (((j >> 3) & 1) << 31));
        zl2 += __int_as_float(pb ^ (((j >> 2) & 1) << 31));
        zl3 += __int_as_float(pb ^ (((j >> 1) & 1) << 31));
        zl4 += __int_as_float(pb ^ ((j & 1) << 31));
    }
    float zv[NQ];
    #pragma unroll
    for (int i = 0; i < 7; ++i)                       // wires 0..6: sign = tid bit (6-i)
        zv[i] = ((tid >> (6 - i)) & 1) ? -psum : psum;
    zv[7] = zl0; zv[8] = zl1; zv[9] = zl2; zv[10] = zl3; zv[11] = zl4;
    #pragma unroll
    for (int q = 0; q < NQ; ++q) {
        float v = zv[q];
        #pragma unroll
        for (int off = 32; off > 0; off >>= 1) v += __shfl_xor(v, off, 64);
        zv[q] = v;
    }
    if (lane == 0) {
        #pragma unroll
        for (int q = 0; q < NQ; ++q) zred[w][q] = zv[q];
    }
    __syncthreads();
    if (tid < NQ)
        out[(size_t)b * NQ + tid] = zred[0][tid] + zred[1][tid];
}

extern "C" void kernel_launch(void* const* d_in, const int* in_sizes, int n_in,
                              void* d_out, int out_size, void* d_ws, size_t ws_size,
                              hipStream_t stream) {
    const float* x     = (const float*)d_in[0];
    const float* prot  = (const float*)d_in[1];
    const float* penta = (const float*)d_in[2];
    float* out = (float*)d_out;
    const int B = in_sizes[0] / (4 * NQ);   // 4096
    qsim_kernel<<<B, NT, 0, stream>>>(x, prot, penta, out);
}

// Round 9
// 172.004 us; speedup vs baseline: 5.7603x; 1.1273x over previous
//
#include <hip/hip_runtime.h>
#include <math.h>

#define NQ   12
#define NL   4
#define NT   128
#define AMPS 32   // per-thread amplitudes; amp = (tid<<5) | j
// state bit 11 = tid bit 6 (wave), bits 10..5 = tid bits 5..0 (lane), bits 4..0 = j

typedef float cplx __attribute__((ext_vector_type(2)));   // VGPR pair for VOP3P

// ---- packed complex arithmetic: 2 instrs per complex mul/fma (v_pk_*_f32)
// d = a*b (complex):  t.lo=ar*br t.hi=ar*bi ; d.lo=-ai*bi+t.lo d.hi=ai*br+t.hi
__device__ __forceinline__ cplx pk_cmul(cplx a, cplx b) {
    cplx t, d;
    asm("v_pk_mul_f32 %0, %1, %2 op_sel:[0,0] op_sel_hi:[0,1]"
        : "=v"(t) : "v"(a), "v"(b));
    asm("v_pk_fma_f32 %0, %1, %2, %3 op_sel:[1,1,0] op_sel_hi:[1,0,1] neg_lo:[1,0,0]"
        : "=v"(d) : "v"(a), "v"(b), "v"(t));
    return d;
}
// d = acc + a*b (complex)
__device__ __forceinline__ cplx pk_cmadd(cplx a, cplx b, cplx acc) {
    cplx t, d;
    asm("v_pk_fma_f32 %0, %1, %2, %3 op_sel:[0,0,0] op_sel_hi:[0,1,1]"
        : "=v"(t) : "v"(a), "v"(b), "v"(acc));
    asm("v_pk_fma_f32 %0, %1, %2, %3 op_sel:[1,1,0] op_sel_hi:[1,0,1] neg_lo:[1,0,0]"
        : "=v"(d) : "v"(a), "v"(b), "v"(t));
    return d;
}

// C = A * B (2x2 complex, row-major m00 m01 m10 m11)
__device__ __forceinline__ void mm2(const cplx* A, const cplx* B, cplx* C) {
    C[0] = pk_cmadd(A[1], B[2], pk_cmul(A[0], B[0]));
    C[1] = pk_cmadd(A[1], B[3], pk_cmul(A[0], B[1]));
    C[2] = pk_cmadd(A[3], B[2], pk_cmul(A[2], B[0]));
    C[3] = pk_cmadd(A[3], B[3], pk_cmul(A[2], B[1]));
}
// PennyLane Rot(phi, theta, omega) = RZ(omega) RY(theta) RZ(phi)
__device__ __forceinline__ void rotmat(float phi, float th, float om, cplx* M) {
    float ct, st_, ca, sa, cd, sd;
    sincosf(0.5f * th, &st_, &ct);
    sincosf(0.5f * (phi + om), &sa, &ca);
    sincosf(0.5f * (phi - om), &sd, &cd);
    M[0] = cplx{ct * ca, -ct * sa};
    M[1] = cplx{-st_ * cd, -st_ * sd};
    M[2] = cplx{st_ * cd, -st_ * sd};
    M[3] = cplx{ct * ca, ct * sa};
}
__device__ __forceinline__ void rowsel(const cplx* M, bool hi, cplx& Mx, cplx& My) {
    Mx = hi ? M[3] : M[0];
    My = hi ? M[2] : M[1];
}

// ---- cross-lane partner fetch for xor mask XM
// xor1/2: DPP quad_perm (explicit source indices). xor8: row_ror:8 (ror8 == xor8 in a 16-row).
// xor4/16/32: __shfl_xor (DS pipe, validated R7).
template<int CTRL>
__device__ __forceinline__ float dpp_perm(float v) {
    return __int_as_float(__builtin_amdgcn_update_dpp(
        __float_as_int(v), __float_as_int(v), CTRL, 0xF, 0xF, false));
}
template<int XM>
__device__ __forceinline__ float partner(float v) {
    if constexpr (XM == 8)      return dpp_perm<0x128>(v);   // row_ror:8
    else if constexpr (XM == 2) return dpp_perm<0x4E>(v);    // quad_perm [2,3,0,1]
    else if constexpr (XM == 1) return dpp_perm<0xB1>(v);    // quad_perm [1,0,3,2]
    else                        return __shfl_xor(v, XM, 64);
}

// gate on a LANE target bit (xor mask XM); per-thread (Mx,My) pre-selected.
template<int XM>
__device__ __forceinline__ void lane_gate(cplx* s, cplx Mx, cplx My) {
    #pragma unroll
    for (int j0 = 0; j0 < AMPS; j0 += 4) {
        cplx pv[4];
        #pragma unroll
        for (int j = 0; j < 4; ++j) {
            pv[j].x = partner<XM>(s[j0 + j].x);
            pv[j].y = partner<XM>(s[j0 + j].y);
        }
        #pragma unroll
        for (int j = 0; j < 4; ++j)
            s[j0 + j] = pk_cmadd(My, pv[j], pk_cmul(Mx, s[j0 + j]));
    }
}
// full 2x2 gate on LOCAL bit K, uniform matrix (per-thread)
template<int K>
__device__ __forceinline__ void local_gate(cplx* s, cplx M0, cplx M1, cplx M2, cplx M3) {
    #pragma unroll
    for (int j = 0; j < AMPS; ++j) {
        if ((j >> K) & 1) continue;
        const int i1 = j | (1 << K);
        cplx v0 = s[j], v1 = s[i1];
        s[j]  = pk_cmadd(M1, v1, pk_cmul(M0, v0));
        s[i1] = pk_cmadd(M3, v1, pk_cmul(M2, v0));
    }
}
// controlled pair-gate: control LOCAL bit CB selects A (c=0) or B (c=1), target LOCAL bit TB
template<int CB, int TB>
__device__ __forceinline__ void cgate_local(cplx* s, const cplx* A, const cplx* B) {
    cplx A0 = A[0], A1 = A[1], A2 = A[2], A3 = A[3];
    cplx B0 = B[0], B1 = B[1], B2 = B[2], B3 = B[3];
    #pragma unroll
    for (int j = 0; j < AMPS; ++j) {
        if ((j >> TB) & 1) continue;
        const int i1 = j | (1 << TB);
        cplx v0 = s[j], v1 = s[i1];
        if ((j >> CB) & 1) {
            s[j]  = pk_cmadd(B1, v1, pk_cmul(B0, v0));
            s[i1] = pk_cmadd(B3, v1, pk_cmul(B2, v0));
        } else {
            s[j]  = pk_cmadd(A1, v1, pk_cmul(A0, v0));
            s[i1] = pk_cmadd(A3, v1, pk_cmul(A2, v0));
        }
    }
}

__global__ __launch_bounds__(NT, 2) void qsim_kernel(
    const float* __restrict__ x,      // (B, 4, NQ)
    const float* __restrict__ prot,   // (NL, NQ, 3)
    const float* __restrict__ penta,  // (NL, NQ, 3)
    float* __restrict__ out)          // (B, NQ)
{
    // xbuf doubles as setup scratch (ENC/RM/EM/UU) and as the exchange buffer.
    __shared__ cplx xbuf[1024];       // 8 KB
    __shared__ cplx GA[NL * NQ][4];   // c=0 branch (persistent)
    __shared__ cplx GB[NL * NQ][4];   // c=1 branch (persistent)
    __shared__ cplx ltab[AMPS];       // layer-0 product over wires 7..11
    __shared__ float zred[2][NQ];

    cplx* ENCp = xbuf;                // 48
    cplx* RMp  = xbuf + 48;           // 192
    cplx* EMp  = xbuf + 240;          // 192
    cplx* UUp  = xbuf + 432;          // 192 (ends at 624 < 1024)

    const int tid  = threadIdx.x;
    const int lane = tid & 63;
    const int w    = tid >> 6;        // wave bit = state bit 11 = wire 0
    const int b    = blockIdx.x;

    // ---- per-sample fused encoding: ENC = RY(x3) RZ(x2) RX(x1) RY(x0)
    if (tid < NQ) {
        const int q = tid;
        const float* xb = x + (size_t)b * 4 * NQ;
        const float t0 = xb[q], t1 = xb[NQ + q], t2 = xb[2 * NQ + q], t3 = xb[3 * NQ + q];
        float c, s;
        sincosf(0.5f * t0, &s, &c);
        cplx R0[4] = {cplx{c, 0.f}, cplx{-s, 0.f}, cplx{s, 0.f}, cplx{c, 0.f}};   // RY
        sincosf(0.5f * t1, &s, &c);
        cplx R1[4] = {cplx{c, 0.f}, cplx{0.f, -s}, cplx{0.f, -s}, cplx{c, 0.f}};  // RX
        sincosf(0.5f * t2, &s, &c);
        cplx R2[4] = {cplx{c, -s}, cplx{0.f, 0.f}, cplx{0.f, 0.f}, cplx{c, s}};   // RZ
        sincosf(0.5f * t3, &s, &c);
        cplx R3[4] = {cplx{c, 0.f}, cplx{-s, 0.f}, cplx{s, 0.f}, cplx{c, 0.f}};   // RY
        cplx T1[4], T2[4], E[4];
        mm2(R1, R0, T1);
        mm2(R2, T1, T2);
        mm2(R3, T2, E);
        #pragma unroll
        for (int i = 0; i < 4; ++i) ENCp[q * 4 + i] = E[i];
    }
    if (tid < NL * NQ) {
        cplx M[4];
        rotmat(prot[3 * tid], prot[3 * tid + 1], prot[3 * tid + 2], M);
        #pragma unroll
        for (int i = 0; i < 4; ++i) RMp[tid * 4 + i] = M[i];
        rotmat(penta[3 * tid], penta[3 * tid + 1], penta[3 * tid + 2], M);
        #pragma unroll
        for (int i = 0; i < 4; ++i) EMp[tid * 4 + i] = M[i];
    }
    __syncthreads();
    if (tid < NL * NQ) {
        cplx U[4];
        mm2(RMp + tid * 4, ENCp + (tid % NQ) * 4, U);
        #pragma unroll
        for (int i = 0; i < 4; ++i) UUp[tid * 4 + i] = U[i];
    }
    __syncthreads();
    // ---- fused controlled-gate pairs (validated round 3/4):
    // q<11:  A = U_{q+1}(l) (I for l=0), B = EM * A
    // q==11: A = U_0(l+1)   (I for l=3), B = A * EM
    if (tid < NL * NQ) {
        const int l = tid / NQ, q = tid - l * NQ;
        cplx A[4], B[4];
        if (q < 11) {
            if (l == 0) { A[0] = cplx{1.f,0.f}; A[1] = cplx{0.f,0.f}; A[2] = cplx{0.f,0.f}; A[3] = cplx{1.f,0.f}; }
            else {
                #pragma unroll
                for (int i = 0; i < 4; ++i) A[i] = UUp[(l * NQ + q + 1) * 4 + i];
            }
            mm2(EMp + tid * 4, A, B);
        } else {
            if (l == NL - 1) { A[0] = cplx{1.f,0.f}; A[1] = cplx{0.f,0.f}; A[2] = cplx{0.f,0.f}; A[3] = cplx{1.f,0.f}; }
            else {
                #pragma unroll
                for (int i = 0; i < 4; ++i) A[i] = UUp[((l + 1) * NQ) * 4 + i];
            }
            mm2(A, EMp + tid * 4, B);
        }
        #pragma unroll
        for (int i = 0; i < 4; ++i) { GA[tid][i] = A[i]; GB[tid][i] = B[i]; }
    }
    // ---- layer-0 local-wire product table (wires 7..11 -> j bits 4..0)
    if (tid >= 64 && tid < 64 + AMPS) {
        const int j = tid - 64;
        cplx m = cplx{1.f, 0.f};
        #pragma unroll
        for (int wq = 7; wq < 12; ++wq) {
            const int bit = (j >> (11 - wq)) & 1;
            m = pk_cmul(m, bit ? UUp[wq * 4 + 2] : UUp[wq * 4 + 0]);
        }
        ltab[j] = m;
    }
    // ---- per-thread lane prefix from layer-0 1q gates (reads UU; before xbuf reuse)
    cplx lp = cplx{1.f, 0.f};
    #pragma unroll
    for (int wq = 0; wq < 7; ++wq) {
        const int bit = (tid >> (6 - wq)) & 1;
        lp = pk_cmul(lp, bit ? UUp[wq * 4 + 2] : UUp[wq * 4 + 0]);
    }
    __syncthreads();

    // ---- init: product state
    cplx s[AMPS];
    #pragma unroll
    for (int j = 0; j < AMPS; ++j) s[j] = pk_cmul(lp, ltab[j]);

    // ---- 48 fused controlled-pair gates
    for (int l = 0; l < NL; ++l) {
        const int g = l * NQ;
        // q=0: c wire0 (wave bit), t wire1 = lane bit5 (xor 32)
        {
            const cplx* M = w ? &GB[g + 0][0] : &GA[g + 0][0];
            cplx Mx, My; rowsel(M, (tid >> 5) & 1, Mx, My);
            lane_gate<32>(s, Mx, My);
        }
        // q=1: c lane5, t lane4 (xor 16)
        {
            const cplx* M = ((tid >> 5) & 1) ? &GB[g + 1][0] : &GA[g + 1][0];
            cplx Mx, My; rowsel(M, (tid >> 4) & 1, Mx, My);
            lane_gate<16>(s, Mx, My);
        }
        // q=2: c lane4, t lane3 (xor 8)
        {
            const cplx* M = ((tid >> 4) & 1) ? &GB[g + 2][0] : &GA[g + 2][0];
            cplx Mx, My; rowsel(M, (tid >> 3) & 1, Mx, My);
            lane_gate<8>(s, Mx, My);
        }
        // q=3: c lane3, t lane2 (xor 4)
        {
            const cplx* M = ((tid >> 3) & 1) ? &GB[g + 3][0] : &GA[g + 3][0];
            cplx Mx, My; rowsel(M, (tid >> 2) & 1, Mx, My);
            lane_gate<4>(s, Mx, My);
        }
        // q=4: c lane2, t lane1 (xor 2)
        {
            const cplx* M = ((tid >> 2) & 1) ? &GB[g + 4][0] : &GA[g + 4][0];
            cplx Mx, My; rowsel(M, (tid >> 1) & 1, Mx, My);
            lane_gate<2>(s, Mx, My);
        }
        // q=5: c lane1, t lane0 (xor 1)
        {
            const cplx* M = ((tid >> 1) & 1) ? &GB[g + 5][0] : &GA[g + 5][0];
            cplx Mx, My; rowsel(M, tid & 1, Mx, My);
            lane_gate<1>(s, Mx, My);
        }
        // q=6: c lane0, t local bit4
        {
            const cplx* M = (tid & 1) ? &GB[g + 6][0] : &GA[g + 6][0];
            local_gate<4>(s, M[0], M[1], M[2], M[3]);
        }
        // q=7..10: both local
        cgate_local<4, 3>(s, &GA[g + 7][0], &GB[g + 7][0]);
        cgate_local<3, 2>(s, &GA[g + 8][0], &GB[g + 8][0]);
        cgate_local<2, 1>(s, &GA[g + 9][0], &GB[g + 9][0]);
        cgate_local<1, 0>(s, &GA[g + 10][0], &GB[g + 10][0]);
        // q=11: c local bit0 (j parity), t wire0 = wave bit -> LDS exchange with tid^64
        // 4 rounds x 8 amps, packed as float4 pairs (even amp -> A, odd -> B)
        {
            cplx Ax, Ay, Bx, By;
            rowsel(&GA[g + 11][0], w, Ax, Ay);
            rowsel(&GB[g + 11][0], w, Bx, By);
            float4* xb4 = (float4*)xbuf;
            #pragma unroll
            for (int r = 0; r < 4; ++r) {
                __syncthreads();
                #pragma unroll
                for (int j2 = 0; j2 < 4; ++j2) {
                    const int j = r * 8 + 2 * j2;
                    xb4[j2 * NT + tid] = make_float4(s[j].x, s[j].y, s[j + 1].x, s[j + 1].y);
                }
                __syncthreads();
                #pragma unroll
                for (int j2 = 0; j2 < 4; ++j2) {
                    float4 f = xb4[j2 * NT + (tid ^ 64)];
                    const int j = r * 8 + 2 * j2;
                    s[j]     = pk_cmadd(Ay, cplx{f.x, f.y}, pk_cmul(Ax, s[j]));
                    s[j + 1] = pk_cmadd(By, cplx{f.z, f.w}, pk_cmul(Bx, s[j + 1]));
                }
            }
        }
    }

    // ---- measurement
    float psum = 0.f;
    float zl0 = 0.f, zl1 = 0.f, zl2 = 0.f, zl3 = 0.f, zl4 = 0.f;  // wires 7..11
    #pragma unroll
    for (int j = 0; j < AMPS; ++j) {
        cplx v = s[j];
        float pr = fmaf(v.x, v.x, v.y * v.y);
        psum += pr;
        int pb = __float_as_int(pr);
        zl0 += __int_as_float(pb ^ (((j >> 4) & 1) << 31));
        zl1 += __int_as_float(pb ^ (((j >> 3) & 1) << 31));
        zl2 += __int_as_float(pb ^ (((j >> 2) & 1) << 31));
        zl3 += __int_as_float(pb ^ (((j >> 1) & 1) << 31));
        zl4 += __int_as_float(pb ^ ((j & 1) << 31));
    }
    float zv[NQ];
    #pragma unroll
    for (int i = 0; i < 7; ++i)                       // wires 0..6: sign = tid bit (6-i)
        zv[i] = ((tid >> (6 - i)) & 1) ? -psum : psum;
    zv[7] = zl0; zv[8] = zl1; zv[9] = zl2; zv[10] = zl3; zv[11] = zl4;
    #pragma unroll
    for (int q = 0; q < NQ; ++q) {
        float v = zv[q];
        #pragma unroll
        for (int off = 32; off > 0; off >>= 1) v += __shfl_xor(v, off, 64);
        zv[q] = v;
    }
    if (lane == 0) {
        #pragma unroll
        for (int q = 0; q < NQ; ++q) zred[w][q] = zv[q];
    }
    __syncthreads();
    if (tid < NQ)
        out[(size_t)b * NQ + tid] = zred[0][tid] + zred[1][tid];
}

extern "C" void kernel_launch(void* const* d_in, const int* in_sizes, int n_in,
                              void* d_out, int out_size, void* d_ws, size_t ws_size,
                              hipStream_t stream) {
    const float* x     = (const float*)d_in[0];
    const float* prot  = (const float*)d_in[1];
    const float* penta = (const float*)d_in[2];
    float* out = (float*)d_out;
    const int B = in_sizes[0] / (4 * NQ);   // 4096
    qsim_kernel<<<B, NT, 0, stream>>>(x, prot, penta, out);
}

// Round 10
// 162.827 us; speedup vs baseline: 6.0849x; 1.0564x over previous
//
#include <hip/hip_runtime.h>
#include <math.h>

#define NQ   12
#define NL   4
#define NT   128
#define AMPS 32   // per-thread amplitudes; amp = (tid<<5) | j
// state bit 11 = tid bit 6 (wave), bits 10..5 = tid bits 5..0 (lane), bits 4..0 = j

typedef float cplx __attribute__((ext_vector_type(2)));   // VGPR pair for VOP3P

// ---- fused complex pair-op: u = Mx*s + My*p, exactly 4 VOP3P instrs, no movs.
// Encodings validated on HW in round 9 (same op_sel/neg_lo patterns, now tied acc).
__device__ __forceinline__ cplx cpair(cplx Mx, cplx s, cplx My, cplx p) {
    cplx u;
    asm("v_pk_mul_f32 %0, %1, %2 op_sel:[0,0] op_sel_hi:[0,1]\n\t"
        "v_pk_fma_f32 %0, %1, %2, %0 op_sel:[1,1,0] op_sel_hi:[1,0,1] neg_lo:[1,0,0]\n\t"
        "v_pk_fma_f32 %0, %3, %4, %0 op_sel:[0,0,0] op_sel_hi:[0,1,1]\n\t"
        "v_pk_fma_f32 %0, %3, %4, %0 op_sel:[1,1,0] op_sel_hi:[1,0,1] neg_lo:[1,0,0]"
        : "=&v"(u) : "v"(Mx), "v"(s), "v"(My), "v"(p));
    return u;
}
// u = a*b (complex), 2 instrs
__device__ __forceinline__ cplx pk_cmul(cplx a, cplx b) {
    cplx u;
    asm("v_pk_mul_f32 %0, %1, %2 op_sel:[0,0] op_sel_hi:[0,1]\n\t"
        "v_pk_fma_f32 %0, %1, %2, %0 op_sel:[1,1,0] op_sel_hi:[1,0,1] neg_lo:[1,0,0]"
        : "=&v"(u) : "v"(a), "v"(b));
    return u;
}

// C = A * B (2x2 complex, row-major m00 m01 m10 m11)
__device__ __forceinline__ void mm2(const cplx* A, const cplx* B, cplx* C) {
    C[0] = cpair(A[0], B[0], A[1], B[2]);
    C[1] = cpair(A[0], B[1], A[1], B[3]);
    C[2] = cpair(A[2], B[0], A[3], B[2]);
    C[3] = cpair(A[2], B[1], A[3], B[3]);
}
// PennyLane Rot(phi, theta, omega) = RZ(omega) RY(theta) RZ(phi)
__device__ __forceinline__ void rotmat(float phi, float th, float om, cplx* M) {
    float ct, st_, ca, sa, cd, sd;
    sincosf(0.5f * th, &st_, &ct);
    sincosf(0.5f * (phi + om), &sa, &ca);
    sincosf(0.5f * (phi - om), &sd, &cd);
    M[0] = cplx{ct * ca, -ct * sa};
    M[1] = cplx{-st_ * cd, -st_ * sd};
    M[2] = cplx{st_ * cd, -st_ * sd};
    M[3] = cplx{ct * ca, ct * sa};
}
__device__ __forceinline__ void rowsel(const cplx* M, bool hi, cplx& Mx, cplx& My) {
    Mx = hi ? M[3] : M[0];
    My = hi ? M[2] : M[1];
}

// ---- cross-lane partner fetch for xor mask XM
// xor1/2: DPP quad_perm. xor8: row_ror:8. xor4/16/32: __shfl_xor (DS pipe). All R9-validated.
template<int CTRL>
__device__ __forceinline__ float dpp_perm(float v) {
    return __int_as_float(__builtin_amdgcn_update_dpp(
        __float_as_int(v), __float_as_int(v), CTRL, 0xF, 0xF, false));
}
template<int XM>
__device__ __forceinline__ float partner(float v) {
    if constexpr (XM == 8)      return dpp_perm<0x128>(v);   // row_ror:8
    else if constexpr (XM == 2) return dpp_perm<0x4E>(v);    // quad_perm [2,3,0,1]
    else if constexpr (XM == 1) return dpp_perm<0xB1>(v);    // quad_perm [1,0,3,2]
    else                        return __shfl_xor(v, XM, 64);
}

// gate on a LANE target bit (xor mask XM); per-thread (Mx,My) pre-selected.
template<int XM>
__device__ __forceinline__ void lane_gate(cplx* s, cplx Mx, cplx My) {
    #pragma unroll
    for (int j0 = 0; j0 < AMPS; j0 += 4) {
        cplx pv[4];
        #pragma unroll
        for (int j = 0; j < 4; ++j) {
            pv[j].x = partner<XM>(s[j0 + j].x);
            pv[j].y = partner<XM>(s[j0 + j].y);
        }
        #pragma unroll
        for (int j = 0; j < 4; ++j)
            s[j0 + j] = cpair(Mx, s[j0 + j], My, pv[j]);
    }
}
// full 2x2 gate on LOCAL bit K, uniform matrix (per-thread)
template<int K>
__device__ __forceinline__ void local_gate(cplx* s, cplx M0, cplx M1, cplx M2, cplx M3) {
    #pragma unroll
    for (int j = 0; j < AMPS; ++j) {
        if ((j >> K) & 1) continue;
        const int i1 = j | (1 << K);
        cplx v0 = s[j], v1 = s[i1];
        s[j]  = cpair(M0, v0, M1, v1);
        s[i1] = cpair(M2, v0, M3, v1);
    }
}
// controlled pair-gate: control LOCAL bit CB selects A (c=0) or B (c=1), target LOCAL bit TB
template<int CB, int TB>
__device__ __forceinline__ void cgate_local(cplx* s, const cplx* A, const cplx* B) {
    cplx A0 = A[0], A1 = A[1], A2 = A[2], A3 = A[3];
    cplx B0 = B[0], B1 = B[1], B2 = B[2], B3 = B[3];
    #pragma unroll
    for (int j = 0; j < AMPS; ++j) {
        if ((j >> TB) & 1) continue;
        const int i1 = j | (1 << TB);
        cplx v0 = s[j], v1 = s[i1];
        if ((j >> CB) & 1) {
            s[j]  = cpair(B0, v0, B1, v1);
            s[i1] = cpair(B2, v0, B3, v1);
        } else {
            s[j]  = cpair(A0, v0, A1, v1);
            s[i1] = cpair(A2, v0, A3, v1);
        }
    }
}

__global__ __launch_bounds__(NT, 2) void qsim_kernel(
    const float* __restrict__ x,      // (B, 4, NQ)
    const float* __restrict__ prot,   // (NL, NQ, 3)
    const float* __restrict__ penta,  // (NL, NQ, 3)
    float* __restrict__ out)          // (B, NQ)
{
    // xbuf doubles as setup scratch (ENC/RM/EM/UU) and as the exchange buffer.
    __shared__ cplx xbuf[1024];       // 8 KB
    __shared__ cplx GA[NL * NQ][4];   // c=0 branch (persistent)
    __shared__ cplx GB[NL * NQ][4];   // c=1 branch (persistent)
    __shared__ cplx ltab[AMPS];       // layer-0 product over wires 7..11
    __shared__ float zred[2][NQ];

    cplx* ENCp = xbuf;                // 48
    cplx* RMp  = xbuf + 48;           // 192
    cplx* EMp  = xbuf + 240;          // 192
    cplx* UUp  = xbuf + 432;          // 192 (ends at 624 < 1024)

    const int tid  = threadIdx.x;
    const int lane = tid & 63;
    const int w    = tid >> 6;        // wave bit = state bit 11 = wire 0
    const int b    = blockIdx.x;

    // ---- per-sample fused encoding: ENC = RY(x3) RZ(x2) RX(x1) RY(x0)
    if (tid < NQ) {
        const int q = tid;
        const float* xb = x + (size_t)b * 4 * NQ;
        const float t0 = xb[q], t1 = xb[NQ + q], t2 = xb[2 * NQ + q], t3 = xb[3 * NQ + q];
        float c, s;
        sincosf(0.5f * t0, &s, &c);
        cplx R0[4] = {cplx{c, 0.f}, cplx{-s, 0.f}, cplx{s, 0.f}, cplx{c, 0.f}};   // RY
        sincosf(0.5f * t1, &s, &c);
        cplx R1[4] = {cplx{c, 0.f}, cplx{0.f, -s}, cplx{0.f, -s}, cplx{c, 0.f}};  // RX
        sincosf(0.5f * t2, &s, &c);
        cplx R2[4] = {cplx{c, -s}, cplx{0.f, 0.f}, cplx{0.f, 0.f}, cplx{c, s}};   // RZ
        sincosf(0.5f * t3, &s, &c);
        cplx R3[4] = {cplx{c, 0.f}, cplx{-s, 0.f}, cplx{s, 0.f}, cplx{c, 0.f}};   // RY
        cplx T1[4], T2[4], E[4];
        mm2(R1, R0, T1);
        mm2(R2, T1, T2);
        mm2(R3, T2, E);
        #pragma unroll
        for (int i = 0; i < 4; ++i) ENCp[q * 4 + i] = E[i];
    }
    if (tid < NL * NQ) {
        cplx M[4];
        rotmat(prot[3 * tid], prot[3 * tid + 1], prot[3 * tid + 2], M);
        #pragma unroll
        for (int i = 0; i < 4; ++i) RMp[tid * 4 + i] = M[i];
        rotmat(penta[3 * tid], penta[3 * tid + 1], penta[3 * tid + 2], M);
        #pragma unroll
        for (int i = 0; i < 4; ++i) EMp[tid * 4 + i] = M[i];
    }
    __syncthreads();
    if (tid < NL * NQ) {
        cplx U[4];
        mm2(RMp + tid * 4, ENCp + (tid % NQ) * 4, U);
        #pragma unroll
        for (int i = 0; i < 4; ++i) UUp[tid * 4 + i] = U[i];
    }
    __syncthreads();
    // ---- fused controlled-gate pairs (validated round 3/4):
    // q<11:  A = U_{q+1}(l) (I for l=0), B = EM * A
    // q==11: A = U_0(l+1)   (I for l=3), B = A * EM
    if (tid < NL * NQ) {
        const int l = tid / NQ, q = tid - l * NQ;
        cplx A[4], B[4];
        if (q < 11) {
            if (l == 0) { A[0] = cplx{1.f,0.f}; A[1] = cplx{0.f,0.f}; A[2] = cplx{0.f,0.f}; A[3] = cplx{1.f,0.f}; }
            else {
                #pragma unroll
                for (int i = 0; i < 4; ++i) A[i] = UUp[(l * NQ + q + 1) * 4 + i];
            }
            mm2(EMp + tid * 4, A, B);
        } else {
            if (l == NL - 1) { A[0] = cplx{1.f,0.f}; A[1] = cplx{0.f,0.f}; A[2] = cplx{0.f,0.f}; A[3] = cplx{1.f,0.f}; }
            else {
                #pragma unroll
                for (int i = 0; i < 4; ++i) A[i] = UUp[((l + 1) * NQ) * 4 + i];
            }
            mm2(A, EMp + tid * 4, B);
        }
        #pragma unroll
        for (int i = 0; i < 4; ++i) { GA[tid][i] = A[i]; GB[tid][i] = B[i]; }
    }
    // ---- layer-0 local-wire product table (wires 7..11 -> j bits 4..0)
    if (tid >= 64 && tid < 64 + AMPS) {
        const int j = tid - 64;
        cplx m = cplx{1.f, 0.f};
        #pragma unroll
        for (int wq = 7; wq < 12; ++wq) {
            const int bit = (j >> (11 - wq)) & 1;
            m = pk_cmul(m, bit ? UUp[wq * 4 + 2] : UUp[wq * 4 + 0]);
        }
        ltab[j] = m;
    }
    // ---- per-thread lane prefix from layer-0 1q gates (reads UU; before xbuf reuse)
    cplx lp = cplx{1.f, 0.f};
    #pragma unroll
    for (int wq = 0; wq < 7; ++wq) {
        const int bit = (tid >> (6 - wq)) & 1;
        lp = pk_cmul(lp, bit ? UUp[wq * 4 + 2] : UUp[wq * 4 + 0]);
    }
    __syncthreads();

    // ---- init: product state
    cplx s[AMPS];
    #pragma unroll
    for (int j = 0; j < AMPS; ++j) s[j] = pk_cmul(lp, ltab[j]);

    // ---- 48 fused controlled-pair gates
    for (int l = 0; l < NL; ++l) {
        const int g = l * NQ;
        // q=0: c wire0 (wave bit), t wire1 = lane bit5 (xor 32)
        {
            const cplx* M = w ? &GB[g + 0][0] : &GA[g + 0][0];
            cplx Mx, My; rowsel(M, (tid >> 5) & 1, Mx, My);
            lane_gate<32>(s, Mx, My);
        }
        // q=1: c lane5, t lane4 (xor 16)
        {
            const cplx* M = ((tid >> 5) & 1) ? &GB[g + 1][0] : &GA[g + 1][0];
            cplx Mx, My; rowsel(M, (tid >> 4) & 1, Mx, My);
            lane_gate<16>(s, Mx, My);
        }
        // q=2: c lane4, t lane3 (xor 8)
        {
            const cplx* M = ((tid >> 4) & 1) ? &GB[g + 2][0] : &GA[g + 2][0];
            cplx Mx, My; rowsel(M, (tid >> 3) & 1, Mx, My);
            lane_gate<8>(s, Mx, My);
        }
        // q=3: c lane3, t lane2 (xor 4)
        {
            const cplx* M = ((tid >> 3) & 1) ? &GB[g + 3][0] : &GA[g + 3][0];
            cplx Mx, My; rowsel(M, (tid >> 2) & 1, Mx, My);
            lane_gate<4>(s, Mx, My);
        }
        // q=4: c lane2, t lane1 (xor 2)
        {
            const cplx* M = ((tid >> 2) & 1) ? &GB[g + 4][0] : &GA[g + 4][0];
            cplx Mx, My; rowsel(M, (tid >> 1) & 1, Mx, My);
            lane_gate<2>(s, Mx, My);
        }
        // q=5: c lane1, t lane0 (xor 1)
        {
            const cplx* M = ((tid >> 1) & 1) ? &GB[g + 5][0] : &GA[g + 5][0];
            cplx Mx, My; rowsel(M, tid & 1, Mx, My);
            lane_gate<1>(s, Mx, My);
        }
        // q=6: c lane0, t local bit4
        {
            const cplx* M = (tid & 1) ? &GB[g + 6][0] : &GA[g + 6][0];
            local_gate<4>(s, M[0], M[1], M[2], M[3]);
        }
        // q=7..10: both local
        cgate_local<4, 3>(s, &GA[g + 7][0], &GB[g + 7][0]);
        cgate_local<3, 2>(s, &GA[g + 8][0], &GB[g + 8][0]);
        cgate_local<2, 1>(s, &GA[g + 9][0], &GB[g + 9][0]);
        cgate_local<1, 0>(s, &GA[g + 10][0], &GB[g + 10][0]);
        // q=11: c local bit0 (j parity), t wire0 = wave bit -> LDS exchange with tid^64
        // 4 rounds x 8 amps, packed as float4 pairs (even amp -> A, odd -> B)
        {
            cplx Ax, Ay, Bx, By;
            rowsel(&GA[g + 11][0], w, Ax, Ay);
            rowsel(&GB[g + 11][0], w, Bx, By);
            float4* xb4 = (float4*)xbuf;
            #pragma unroll
            for (int r = 0; r < 4; ++r) {
                __syncthreads();
                #pragma unroll
                for (int j2 = 0; j2 < 4; ++j2) {
                    const int j = r * 8 + 2 * j2;
                    xb4[j2 * NT + tid] = make_float4(s[j].x, s[j].y, s[j + 1].x, s[j + 1].y);
                }
                __syncthreads();
                #pragma unroll
                for (int j2 = 0; j2 < 4; ++j2) {
                    float4 f = xb4[j2 * NT + (tid ^ 64)];
                    const int j = r * 8 + 2 * j2;
                    s[j]     = cpair(Ax, s[j],     Ay, cplx{f.x, f.y});
                    s[j + 1] = cpair(Bx, s[j + 1], By, cplx{f.z, f.w});
                }
            }
        }
    }

    // ---- measurement
    float psum = 0.f;
    float zl0 = 0.f, zl1 = 0.f, zl2 = 0.f, zl3 = 0.f, zl4 = 0.f;  // wires 7..11
    #pragma unroll
    for (int j = 0; j < AMPS; ++j) {
        cplx v = s[j];
        float pr = fmaf(v.x, v.x, v.y * v.y);
        psum += pr;
        int pb = __float_as_int(pr);
        zl0 += __int_as_float(pb ^ (((j >> 4) & 1) << 31));
        zl1 += __int_as_float(pb ^ (((j >> 3) & 1) << 31));
        zl2 += __int_as_float(pb ^ (((j >> 2) & 1) << 31));
        zl3 += __int_as_float(pb ^ (((j >> 1) & 1) << 31));
        zl4 += __int_as_float(pb ^ ((j & 1) << 31));
    }
    float zv[NQ];
    #pragma unroll
    for (int i = 0; i < 7; ++i)                       // wires 0..6: sign = tid bit (6-i)
        zv[i] = ((tid >> (6 - i)) & 1) ? -psum : psum;
    zv[7] = zl0; zv[8] = zl1; zv[9] = zl2; zv[10] = zl3; zv[11] = zl4;
    #pragma unroll
    for (int q = 0; q < NQ; ++q) {
        float v = zv[q];
        #pragma unroll
        for (int off = 32; off > 0; off >>= 1) v += __shfl_xor(v, off, 64);
        zv[q] = v;
    }
    if (lane == 0) {
        #pragma unroll
        for (int q = 0; q < NQ; ++q) zred[w][q] = zv[q];
    }
    __syncthreads();
    if (tid < NQ)
        out[(size_t)b * NQ + tid] = zred[0][tid] + zred[1][tid];
}

extern "C" void kernel_launch(void* const* d_in, const int* in_sizes, int n_in,
                              void* d_out, int out_size, void* d_ws, size_t ws_size,
                              hipStream_t stream) {
    const float* x     = (const float*)d_in[0];
    const float* prot  = (const float*)d_in[1];
    const float* penta = (const float*)d_in[2];
    float* out = (float*)d_out;
    const int B = in_sizes[0] / (4 * NQ);   // 4096
    qsim_kernel<<<B, NT, 0, stream>>>(x, prot, penta, out);
}

// Round 11
// 157.381 us; speedup vs baseline: 6.2955x; 1.0346x over previous
//
#include <hip/hip_runtime.h>
#include <math.h>

#define NQ   12
#define NL   4
#define NT   64
#define AMPS 64   // per-thread amplitudes; amp = (lane<<6) | j
// state bits 11..6 = lane bits 5..0 (wires 0..5); state bits 5..0 = j bits 5..0 (wires 6..11)

typedef float cplx __attribute__((ext_vector_type(2)));   // VGPR pair for VOP3P

// ---- fused complex pair-op: u = Mx*s + My*p, exactly 4 VOP3P instrs (R10-validated)
__device__ __forceinline__ cplx cpair(cplx Mx, cplx s, cplx My, cplx p) {
    cplx u;
    asm("v_pk_mul_f32 %0, %1, %2 op_sel:[0,0] op_sel_hi:[0,1]\n\t"
        "v_pk_fma_f32 %0, %1, %2, %0 op_sel:[1,1,0] op_sel_hi:[1,0,1] neg_lo:[1,0,0]\n\t"
        "v_pk_fma_f32 %0, %3, %4, %0 op_sel:[0,0,0] op_sel_hi:[0,1,1]\n\t"
        "v_pk_fma_f32 %0, %3, %4, %0 op_sel:[1,1,0] op_sel_hi:[1,0,1] neg_lo:[1,0,0]"
        : "=&v"(u) : "v"(Mx), "v"(s), "v"(My), "v"(p));
    return u;
}
// u = a*b (complex), 2 instrs (R9-validated)
__device__ __forceinline__ cplx pk_cmul(cplx a, cplx b) {
    cplx u;
    asm("v_pk_mul_f32 %0, %1, %2 op_sel:[0,0] op_sel_hi:[0,1]\n\t"
        "v_pk_fma_f32 %0, %1, %2, %0 op_sel:[1,1,0] op_sel_hi:[1,0,1] neg_lo:[1,0,0]"
        : "=&v"(u) : "v"(a), "v"(b));
    return u;
}

// C = A * B (2x2 complex, row-major m00 m01 m10 m11)
__device__ __forceinline__ void mm2(const cplx* A, const cplx* B, cplx* C) {
    C[0] = cpair(A[0], B[0], A[1], B[2]);
    C[1] = cpair(A[0], B[1], A[1], B[3]);
    C[2] = cpair(A[2], B[0], A[3], B[2]);
    C[3] = cpair(A[2], B[1], A[3], B[3]);
}
// PennyLane Rot(phi, theta, omega) = RZ(omega) RY(theta) RZ(phi)
__device__ __forceinline__ void rotmat(float phi, float th, float om, cplx* M) {
    float ct, st_, ca, sa, cd, sd;
    sincosf(0.5f * th, &st_, &ct);
    sincosf(0.5f * (phi + om), &sa, &ca);
    sincosf(0.5f * (phi - om), &sd, &cd);
    M[0] = cplx{ct * ca, -ct * sa};
    M[1] = cplx{-st_ * cd, -st_ * sd};
    M[2] = cplx{st_ * cd, -st_ * sd};
    M[3] = cplx{ct * ca, ct * sa};
}
__device__ __forceinline__ void rowsel(const cplx* M, bool hi, cplx& Mx, cplx& My) {
    Mx = hi ? M[3] : M[0];
    My = hi ? M[2] : M[1];
}

// ---- cross-lane partner fetch for xor mask XM (all primitives R9/R10-validated)
template<int CTRL>
__device__ __forceinline__ float dpp_perm(float v) {
    return __int_as_float(__builtin_amdgcn_update_dpp(
        __float_as_int(v), __float_as_int(v), CTRL, 0xF, 0xF, false));
}
template<int XM>
__device__ __forceinline__ float partner(float v) {
    if constexpr (XM == 8)      return dpp_perm<0x128>(v);   // row_ror:8
    else if constexpr (XM == 2) return dpp_perm<0x4E>(v);    // quad_perm [2,3,0,1]
    else if constexpr (XM == 1) return dpp_perm<0xB1>(v);    // quad_perm [1,0,3,2]
    else                        return __shfl_xor(v, XM, 64);
}

// gate on a LANE target bit (xor mask XM); per-thread (Mx,My) pre-selected.
template<int XM>
__device__ __forceinline__ void lane_gate(cplx* s, cplx Mx, cplx My) {
    #pragma unroll
    for (int j0 = 0; j0 < AMPS; j0 += 4) {
        cplx pv[4];
        #pragma unroll
        for (int j = 0; j < 4; ++j) {
            pv[j].x = partner<XM>(s[j0 + j].x);
            pv[j].y = partner<XM>(s[j0 + j].y);
        }
        #pragma unroll
        for (int j = 0; j < 4; ++j)
            s[j0 + j] = cpair(Mx, s[j0 + j], My, pv[j]);
    }
}
// full 2x2 gate on LOCAL bit K, uniform matrix (per-thread)
template<int K>
__device__ __forceinline__ void local_gate(cplx* s, cplx M0, cplx M1, cplx M2, cplx M3) {
    #pragma unroll
    for (int j = 0; j < AMPS; ++j) {
        if ((j >> K) & 1) continue;
        const int i1 = j | (1 << K);
        cplx v0 = s[j], v1 = s[i1];
        s[j]  = cpair(M0, v0, M1, v1);
        s[i1] = cpair(M2, v0, M3, v1);
    }
}
// controlled pair-gate: control LOCAL bit CB selects A (c=0) or B (c=1), target LOCAL bit TB
template<int CB, int TB>
__device__ __forceinline__ void cgate_local(cplx* s, const cplx* A, const cplx* B) {
    cplx A0 = A[0], A1 = A[1], A2 = A[2], A3 = A[3];
    cplx B0 = B[0], B1 = B[1], B2 = B[2], B3 = B[3];
    #pragma unroll
    for (int j = 0; j < AMPS; ++j) {
        if ((j >> TB) & 1) continue;
        const int i1 = j | (1 << TB);
        cplx v0 = s[j], v1 = s[i1];
        if ((j >> CB) & 1) {
            s[j]  = cpair(B0, v0, B1, v1);
            s[i1] = cpair(B2, v0, B3, v1);
        } else {
            s[j]  = cpair(A0, v0, A1, v1);
            s[i1] = cpair(A2, v0, A3, v1);
        }
    }
}

__global__ __launch_bounds__(NT, 1) void qsim_kernel(
    const float* __restrict__ x,      // (B, 4, NQ)
    const float* __restrict__ prot,   // (NL, NQ, 3)
    const float* __restrict__ penta,  // (NL, NQ, 3)
    float* __restrict__ out)          // (B, NQ)
{
    __shared__ cplx xbuf[640];        // setup scratch: ENC/RM/EM/UU
    __shared__ cplx GA[NL * NQ][4];   // c=0 branch (persistent)
    __shared__ cplx GB[NL * NQ][4];   // c=1 branch (persistent)
    __shared__ cplx ltab[AMPS];       // layer-0 product over wires 6..11

    cplx* ENCp = xbuf;                // 48
    cplx* RMp  = xbuf + 48;           // 192
    cplx* EMp  = xbuf + 240;          // 192
    cplx* UUp  = xbuf + 432;          // 192 (ends at 624)

    const int tid = threadIdx.x;      // == lane, 0..63
    const int b   = blockIdx.x;

    // ---- per-sample fused encoding: ENC = RY(x3) RZ(x2) RX(x1) RY(x0)
    if (tid < NQ) {
        const int q = tid;
        const float* xb = x + (size_t)b * 4 * NQ;
        const float t0 = xb[q], t1 = xb[NQ + q], t2 = xb[2 * NQ + q], t3 = xb[3 * NQ + q];
        float c, s;
        sincosf(0.5f * t0, &s, &c);
        cplx R0[4] = {cplx{c, 0.f}, cplx{-s, 0.f}, cplx{s, 0.f}, cplx{c, 0.f}};   // RY
        sincosf(0.5f * t1, &s, &c);
        cplx R1[4] = {cplx{c, 0.f}, cplx{0.f, -s}, cplx{0.f, -s}, cplx{c, 0.f}};  // RX
        sincosf(0.5f * t2, &s, &c);
        cplx R2[4] = {cplx{c, -s}, cplx{0.f, 0.f}, cplx{0.f, 0.f}, cplx{c, s}};   // RZ
        sincosf(0.5f * t3, &s, &c);
        cplx R3[4] = {cplx{c, 0.f}, cplx{-s, 0.f}, cplx{s, 0.f}, cplx{c, 0.f}};   // RY
        cplx T1[4], T2[4], E[4];
        mm2(R1, R0, T1);
        mm2(R2, T1, T2);
        mm2(R3, T2, E);
        #pragma unroll
        for (int i = 0; i < 4; ++i) ENCp[q * 4 + i] = E[i];
    }
    if (tid < NL * NQ) {
        cplx M[4];
        rotmat(prot[3 * tid], prot[3 * tid + 1], prot[3 * tid + 2], M);
        #pragma unroll
        for (int i = 0; i < 4; ++i) RMp[tid * 4 + i] = M[i];
        rotmat(penta[3 * tid], penta[3 * tid + 1], penta[3 * tid + 2], M);
        #pragma unroll
        for (int i = 0; i < 4; ++i) EMp[tid * 4 + i] = M[i];
    }
    __syncthreads();
    if (tid < NL * NQ) {
        cplx U[4];
        mm2(RMp + tid * 4, ENCp + (tid % NQ) * 4, U);
        #pragma unroll
        for (int i = 0; i < 4; ++i) UUp[tid * 4 + i] = U[i];
    }
    __syncthreads();
    // ---- fused controlled-gate pairs (validated rounds 3-10):
    // q<11:  A = U_{q+1}(l) (I for l=0), B = EM * A
    // q==11: A = U_0(l+1)   (I for l=3), B = A * EM
    if (tid < NL * NQ) {
        const int l = tid / NQ, q = tid - l * NQ;
        cplx A[4], B[4];
        if (q < 11) {
            if (l == 0) { A[0] = cplx{1.f,0.f}; A[1] = cplx{0.f,0.f}; A[2] = cplx{0.f,0.f}; A[3] = cplx{1.f,0.f}; }
            else {
                #pragma unroll
                for (int i = 0; i < 4; ++i) A[i] = UUp[(l * NQ + q + 1) * 4 + i];
            }
            mm2(EMp + tid * 4, A, B);
        } else {
            if (l == NL - 1) { A[0] = cplx{1.f,0.f}; A[1] = cplx{0.f,0.f}; A[2] = cplx{0.f,0.f}; A[3] = cplx{1.f,0.f}; }
            else {
                #pragma unroll
                for (int i = 0; i < 4; ++i) A[i] = UUp[((l + 1) * NQ) * 4 + i];
            }
            mm2(A, EMp + tid * 4, B);
        }
        #pragma unroll
        for (int i = 0; i < 4; ++i) { GA[tid][i] = A[i]; GB[tid][i] = B[i]; }
    }
    // ---- layer-0 local-wire product table (wires 6..11 -> j bits 5..0), one entry per thread
    {
        cplx m = cplx{1.f, 0.f};
        #pragma unroll
        for (int wq = 6; wq < 12; ++wq) {
            const int bit = (tid >> (11 - wq)) & 1;
            m = pk_cmul(m, bit ? UUp[wq * 4 + 2] : UUp[wq * 4 + 0]);
        }
        ltab[tid] = m;
    }
    // ---- per-thread lane prefix from layer-0 1q gates on wires 0..5 (lane bits 5..0)
    cplx lp = cplx{1.f, 0.f};
    #pragma unroll
    for (int wq = 0; wq < 6; ++wq) {
        const int bit = (tid >> (5 - wq)) & 1;
        lp = pk_cmul(lp, bit ? UUp[wq * 4 + 2] : UUp[wq * 4 + 0]);
    }
    __syncthreads();

    // ---- init: product state
    cplx s[AMPS];
    #pragma unroll
    for (int j = 0; j < AMPS; ++j) s[j] = pk_cmul(lp, ltab[j]);

    // ---- 48 fused controlled-pair gates, ZERO barriers, zero LDS exchange
    for (int l = 0; l < NL; ++l) {
        const int g = l * NQ;
        // q=0: c wire0 (lane bit5), t wire1 (lane bit4, xor16)
        {
            const cplx* M = (tid & 32) ? &GB[g + 0][0] : &GA[g + 0][0];
            cplx Mx, My; rowsel(M, tid & 16, Mx, My);
            lane_gate<16>(s, Mx, My);
        }
        // q=1: c lane4, t lane3 (xor8, DPP)
        {
            const cplx* M = (tid & 16) ? &GB[g + 1][0] : &GA[g + 1][0];
            cplx Mx, My; rowsel(M, tid & 8, Mx, My);
            lane_gate<8>(s, Mx, My);
        }
        // q=2: c lane3, t lane2 (xor4)
        {
            const cplx* M = (tid & 8) ? &GB[g + 2][0] : &GA[g + 2][0];
            cplx Mx, My; rowsel(M, tid & 4, Mx, My);
            lane_gate<4>(s, Mx, My);
        }
        // q=3: c lane2, t lane1 (xor2, DPP)
        {
            const cplx* M = (tid & 4) ? &GB[g + 3][0] : &GA[g + 3][0];
            cplx Mx, My; rowsel(M, tid & 2, Mx, My);
            lane_gate<2>(s, Mx, My);
        }
        // q=4: c lane1, t lane0 (xor1, DPP)
        {
            const cplx* M = (tid & 2) ? &GB[g + 4][0] : &GA[g + 4][0];
            cplx Mx, My; rowsel(M, tid & 1, Mx, My);
            lane_gate<1>(s, Mx, My);
        }
        // q=5: c lane0, t local bit5
        {
            const cplx* M = (tid & 1) ? &GB[g + 5][0] : &GA[g + 5][0];
            local_gate<5>(s, M[0], M[1], M[2], M[3]);
        }
        // q=6..10: both local
        cgate_local<5, 4>(s, &GA[g + 6][0], &GB[g + 6][0]);
        cgate_local<4, 3>(s, &GA[g + 7][0], &GB[g + 7][0]);
        cgate_local<3, 2>(s, &GA[g + 8][0], &GB[g + 8][0]);
        cgate_local<2, 1>(s, &GA[g + 9][0], &GB[g + 9][0]);
        cgate_local<1, 0>(s, &GA[g + 10][0], &GB[g + 10][0]);
        // q=11: c local bit0 (j parity), t wire0 (lane bit5) -> xor32 shuffle, per-amp A/B
        {
            cplx Ax, Ay, Bx, By;
            rowsel(&GA[g + 11][0], tid & 32, Ax, Ay);
            rowsel(&GB[g + 11][0], tid & 32, Bx, By);
            #pragma unroll
            for (int j0 = 0; j0 < AMPS; j0 += 4) {
                cplx pv[4];
                #pragma unroll
                for (int j = 0; j < 4; ++j) {
                    pv[j].x = __shfl_xor(s[j0 + j].x, 32, 64);
                    pv[j].y = __shfl_xor(s[j0 + j].y, 32, 64);
                }
                #pragma unroll
                for (int j = 0; j < 4; ++j) {
                    if ((j0 + j) & 1) s[j0 + j] = cpair(Bx, s[j0 + j], By, pv[j]);
                    else              s[j0 + j] = cpair(Ax, s[j0 + j], Ay, pv[j]);
                }
            }
        }
    }

    // ---- measurement: z_i over state bit (11-i); amp = (tid<<6)|j
    float psum = 0.f;
    float zl[6] = {0.f, 0.f, 0.f, 0.f, 0.f, 0.f};   // wires 6..11 (j bits 5..0)
    #pragma unroll
    for (int j = 0; j < AMPS; ++j) {
        cplx v = s[j];
        float pr = fmaf(v.x, v.x, v.y * v.y);
        psum += pr;
        int pb = __float_as_int(pr);
        #pragma unroll
        for (int i = 0; i < 6; ++i)
            zl[i] += __int_as_float(pb ^ (((j >> (5 - i)) & 1) << 31));
    }
    float zv[NQ];
    #pragma unroll
    for (int i = 0; i < 6; ++i)                      // wires 0..5: sign = lane bit (5-i)
        zv[i] = ((tid >> (5 - i)) & 1) ? -psum : psum;
    #pragma unroll
    for (int i = 0; i < 6; ++i) zv[6 + i] = zl[i];
    #pragma unroll
    for (int q = 0; q < NQ; ++q) {
        float v = zv[q];
        #pragma unroll
        for (int off = 32; off > 0; off >>= 1) v += __shfl_xor(v, off, 64);
        zv[q] = v;
    }
    if (tid == 0) {
        float* ob = out + (size_t)b * NQ;
        #pragma unroll
        for (int q = 0; q < NQ; ++q) ob[q] = zv[q];
    }
}

extern "C" void kernel_launch(void* const* d_in, const int* in_sizes, int n_in,
                              void* d_out, int out_size, void* d_ws, size_t ws_size,
                              hipStream_t stream) {
    const float* x     = (const float*)d_in[0];
    const float* prot  = (const float*)d_in[1];
    const float* penta = (const float*)d_in[2];
    float* out = (float*)d_out;
    const int B = in_sizes[0] / (4 * NQ);   // 4096
    qsim_kernel<<<B, NT, 0, stream>>>(x, prot, penta, out);
}